// Round 11
// baseline (303.406 us; speedup 1.0000x reference)
//
#include <hip/hip_runtime.h>
#include <math.h>

#define SEQ 4096
#define CH  256
#define NHT 8      // N * HEADS
#define DHD 64

// Q is pre-scaled by log2(e)/64 at projection time, so both attention passes
// compute exp2(S) with zero multiplies.
#define QSCALE 0.0225421092f

using bf16x8 = __attribute__((ext_vector_type(8))) short;
using f32x4  = __attribute__((ext_vector_type(4))) float;
typedef unsigned short u16;
typedef unsigned int   u32;

__device__ __forceinline__ u16 f2bf(float f) {
    u32 u = __float_as_uint(f);
    u = (u + 0x7fffu + ((u >> 16) & 1u)) >> 16;
    return (u16)u;
}
__device__ __forceinline__ float bf2f(u16 h) {
    return __uint_as_float(((u32)h) << 16);
}
// raw v_exp_f32 — exp2f without -ffast-math is an OCML call (~8 VALU ops)
__device__ __forceinline__ float fexp2(float x) {
    return __builtin_amdgcn_exp2f(x);
}

// ---------------------------------------------------------------------------
// Prep: weight pack (blocks 0..1279) + LN1 (blocks 1280..1535), one launch.
// ---------------------------------------------------------------------------
__global__ __launch_bounds__(256) void k_prep(const float* __restrict__ x,
                                              const float* __restrict__ ln1w,
                                              const float* __restrict__ ln1b,
                                              const float* __restrict__ WQ,
                                              const float* __restrict__ WK,
                                              const float* __restrict__ WV,
                                              const float* __restrict__ W1,
                                              const float* __restrict__ W2,
                                              u16* __restrict__ norm,
                                              u16* __restrict__ BtQKV,
                                              u16* __restrict__ W1t,
                                              u16* __restrict__ W2t)
{
    __shared__ float tile[32][257];
    __shared__ float mu[32], rs[32];
    int bid = blockIdx.x;
    int t = threadIdx.x;
    if (bid < 1280) {   // ---- pack ----
        int id = bid * 256 + t;
        if (id < 768 * 256) {
            int j = id >> 8, c = id & 255;
            int which = j >> 8, h = (j >> 6) & 3, d = j & 63;
            const float* W = (which == 0) ? WQ : (which == 1) ? WK : WV;
            BtQKV[id] = f2bf(W[(h * 256 + c) * 64 + d]);
        } else if (id < 768 * 256 + 65536) {
            int jj = id - 768 * 256;
            int j = jj >> 8, c = jj & 255;
            W1t[jj] = f2bf(W1[c * 256 + j]);
        } else if (id < 768 * 256 + 2 * 65536) {
            int jj = id - 768 * 256 - 65536;
            int j = jj >> 8, c = jj & 255;
            W2t[jj] = f2bf(W2[c * 256 + j]);
        }
        return;
    }
    // ---- LN1 ----
    int b2i = bid - 1280;
    int n = b2i >> 7, s0 = (b2i & 127) * 32;
    int sl = t & 31, cg = t >> 5;
    for (int cc = 0; cc < 256; cc += 8) {
        int c = cc + cg;
        tile[sl][c] = x[(n * 256 + c) * SEQ + s0 + sl];
    }
    __syncthreads();
    int wv = t >> 6, l = t & 63;
    for (int rr = 0; rr < 8; rr++) {
        int s = wv * 8 + rr;
        float a0 = tile[s][l], a1 = tile[s][l + 64], a2 = tile[s][l + 128], a3 = tile[s][l + 192];
        float sm = a0 + a1 + a2 + a3;
        float sq = a0 * a0 + a1 * a1 + a2 * a2 + a3 * a3;
        for (int off = 32; off; off >>= 1) { sm += __shfl_xor(sm, off); sq += __shfl_xor(sq, off); }
        if (l == 0) {
            float m = sm * (1.f / 256.f);
            mu[s] = m;
            rs[s] = rsqrtf(sq * (1.f / 256.f) - m * m + 1e-5f);
        }
    }
    __syncthreads();
    float ww = ln1w[t], bb = ln1b[t];
    for (int s = 0; s < 32; s++) {
        float v = (tile[s][t] - mu[s]) * rs[s] * ww + bb;
        norm[(n * SEQ + s0 + s) * 256 + t] = f2bf(v);
    }
}

// ---------------------------------------------------------------------------
// QKV projection, barrier-free (R4-proven). Q pre-scaled by QSCALE.
// V written transposed in FP32 (Vf[nh][d][k]); k_vdiv rounds to bf16 once.
// ---------------------------------------------------------------------------
__global__ __launch_bounds__(256) void k_qkv(const u16* __restrict__ norm,
                                             const u16* __restrict__ Bt,
                                             u16* __restrict__ Qo,
                                             u16* __restrict__ Ko,
                                             float* __restrict__ Vfo)
{
    int m0 = blockIdx.x * 64, j0 = blockIdx.y * 128;
    int t = threadIdx.x, w = t >> 6, lane = t & 63, quad = lane >> 4, l16 = lane & 15;
    const u16* Ap = norm + (long)(m0 + w * 16 + l16) * 256;
    const u16* Bp = Bt + (long)j0 * 256;
    f32x4 z = {0.f, 0.f, 0.f, 0.f};
    f32x4 acc[8];
    #pragma unroll
    for (int j = 0; j < 8; j++) acc[j] = z;
    #pragma unroll
    for (int kc = 0; kc < 8; kc++) {
        bf16x8 a = *(const bf16x8*)&Ap[kc * 32 + quad * 8];
        #pragma unroll
        for (int j = 0; j < 8; j++) {
            bf16x8 b = *(const bf16x8*)&Bp[(long)(j * 16 + l16) * 256 + kc * 32 + quad * 8];
            acc[j] = __builtin_amdgcn_mfma_f32_16x16x32_bf16(a, b, acc[j], 0, 0, 0);
        }
    }
    #pragma unroll
    for (int j = 0; j < 8; j++) {
        int col = j0 + j * 16 + l16;
        int which = col >> 8, h = (col >> 6) & 3, d = col & 63;
        int m = m0 + w * 16 + quad * 4;
        int n = m >> 12, s = m & 4095;
        if (which == 2) {
            float4 o = make_float4(acc[j][0], acc[j][1], acc[j][2], acc[j][3]);
            *(float4*)&Vfo[((long)(n * 4 + h) * 64 + d) * SEQ + s] = o;
        } else {
            u16* dst = (which == 0) ? Qo : Ko;
            float sc = (which == 0) ? QSCALE : 1.0f;
            #pragma unroll
            for (int r = 0; r < 4; r++)
                dst[((n * 4 + h) * SEQ + s + r) * 64 + d] = f2bf(acc[j][r] * sc);
        }
    }
}

// ---------------------------------------------------------------------------
// XCD-group swizzles (R16-proven: FETCH 37.5->8.3 MB).
// 1024-block grids: 32 groups x 32 sub-blocks; group g on XCD g>>2.
// ---------------------------------------------------------------------------
__device__ __forceinline__ void xcd_decode32(int s, int& g, int& sub) {
    int xcd = s & 7, m = s >> 3;
    g = xcd * 4 + (m >> 5);
    sub = m & 31;
}

// ---------------------------------------------------------------------------
// Pass 1 (R21-proven): qc=4 grid + __launch_bounds__(256,3).
// ---------------------------------------------------------------------------
__global__ __launch_bounds__(256, 3) void k_pass1(const u16* __restrict__ Q,
                                                  const u16* __restrict__ Km,
                                                  float* __restrict__ D2)
{
    __shared__ float Dred[128];
    int g, sub;
    xcd_decode32(blockIdx.x, g, sub);
    int nh = g & 7, qc = g >> 3, k0 = sub * 128;
    const u16* Qh = Q + (long)nh * SEQ * 64;
    const u16* Kh = Km + (long)nh * SEQ * 64;
    int t = threadIdx.x, w = t >> 6, lane = t & 63, quad = lane >> 4, l16 = lane & 15;
    bf16x8 Kf[8][2];
    #pragma unroll
    for (int i = 0; i < 8; i++) {
        Kf[i][0] = *(const bf16x8*)&Kh[(k0 + i * 16 + l16) * 64 + quad * 8];
        Kf[i][1] = *(const bf16x8*)&Kh[(k0 + i * 16 + l16) * 64 + 32 + quad * 8];
    }
    if (t < 128) Dred[t] = 0.f;
    f32x4 z = {0.f, 0.f, 0.f, 0.f};
    float Dacc[8][4] = {};
    const int qw0 = qc * 1024 + w * 256;

#define P1_LOADQ(B0, B1, ST)                                                  \
    {                                                                         \
        int _q = qw0 + (ST) * 16 + l16;                                       \
        B0 = *(const bf16x8*)&Qh[_q * 64 + quad * 8];                         \
        B1 = *(const bf16x8*)&Qh[_q * 64 + 32 + quad * 8];                    \
    }
#define P1_STEP(B0, B1)                                                       \
    {                                                                         \
        _Pragma("unroll")                                                     \
        for (int i = 0; i < 8; i++) {                                         \
            f32x4 acc = z;                                                    \
            acc = __builtin_amdgcn_mfma_f32_16x16x32_bf16(Kf[i][0], B0, acc, 0, 0, 0); \
            acc = __builtin_amdgcn_mfma_f32_16x16x32_bf16(Kf[i][1], B1, acc, 0, 0, 0); \
            _Pragma("unroll")                                                 \
            for (int r = 0; r < 4; r++) Dacc[i][r] += fexp2(acc[r]);          \
        }                                                                     \
    }

    bf16x8 qa0, qa1, qb0, qb1;
    P1_LOADQ(qa0, qa1, 0)
    P1_LOADQ(qb0, qb1, 1)
    for (int st = 0; st < 16; st += 2) {
        P1_STEP(qa0, qa1)
        if (st + 2 < 16) { P1_LOADQ(qa0, qa1, st + 2) }
        P1_STEP(qb0, qb1)
        if (st + 3 < 16) { P1_LOADQ(qb0, qb1, st + 3) }
    }
#undef P1_LOADQ
#undef P1_STEP

    #pragma unroll
    for (int i = 0; i < 8; i++)
        #pragma unroll
        for (int r = 0; r < 4; r++) {
            float v = Dacc[i][r];
            v += __shfl_xor(v, 1); v += __shfl_xor(v, 2);
            v += __shfl_xor(v, 4); v += __shfl_xor(v, 8);
            Dacc[i][r] = v;
        }
    __syncthreads();
    if (l16 == 0) {
        #pragma unroll
        for (int i = 0; i < 8; i++)
            #pragma unroll
            for (int r = 0; r < 4; r++)
                atomicAdd(&Dred[i * 16 + quad * 4 + r], Dacc[i][r]);
    }
    __syncthreads();
    if (t < 128) D2[((long)(qc * NHT + nh)) * SEQ + k0 + t] = Dred[t];
}

// ---------------------------------------------------------------------------
// V pre-scale (R16-proven): z[q,k] = exp(S)/D[k], so fold 1/D into V once.
// D2 has 4 qc-partials.
// ---------------------------------------------------------------------------
__global__ __launch_bounds__(256) void k_vdiv(const float* __restrict__ Vf,
                                              const float* __restrict__ D2,
                                              u16* __restrict__ Vto)
{
    int b = blockIdx.x;
    int nh = b >> 6, d = b & 63;
    const long QS = (long)NHT * SEQ;
    const float* Dp = D2 + (long)nh * SEQ;
    const float* src = Vf + ((long)nh * 64 + d) * SEQ;
    u16* dst = Vto + ((long)nh * 64 + d) * SEQ;
    int t = threadIdx.x;
    #pragma unroll
    for (int half = 0; half < 2; half++) {
        int k = half * 2048 + t * 8;
        float o[8];
        #pragma unroll
        for (int e = 0; e < 8; e++) {
            float dsum = Dp[k + e] + Dp[QS + k + e] + Dp[2 * QS + k + e] + Dp[3 * QS + k + e];
            o[e] = src[k + e] / dsum;
        }
        uint4 pk;
        pk.x = (u32)f2bf(o[0]) | ((u32)f2bf(o[1]) << 16);
        pk.y = (u32)f2bf(o[2]) | ((u32)f2bf(o[3]) << 16);
        pk.z = (u32)f2bf(o[4]) | ((u32)f2bf(o[5]) << 16);
        pk.w = (u32)f2bf(o[6]) | ((u32)f2bf(o[7]) << 16);
        *(uint4*)&dst[k] = pk;
    }
}

// ---------------------------------------------------------------------------
// Pass 2, R22 (resubmitted R23): R21's 64-k-stripe d-split with kcid 2->4.
// R21 improved via lighter regs/LDS but occupancy stayed 17.8% because the
// GRID was only 512 blocks = 2/CU — resources allowed more, the grid never
// supplied them.  kcid=4: each block streams a 1024-k window (16 stripes),
// grid = 1024 blocks = 4 blocks/CU; (256,4) caps regs at 128 >= 108 live
// (R21 measured 76 VGPR + 32 acc) so no R18-style spill.  Per-wave
// load:compute ratio unchanged.  Cost: acat2 has 4 partials (tail sums 4).
// LDS 34816 x 4 = 139264 <= 160K.
// ---------------------------------------------------------------------------
__global__ __launch_bounds__(256, 4) void k_pass2(const u16* __restrict__ Q,
                                                  const u16* __restrict__ Km,
                                                  const u16* __restrict__ Vt,
                                                  float* __restrict__ acat2)
{
    __shared__ __align__(16) u16 lP2[2][128][68];   // 34816 B
    float (*red)[68] = (float(*)[68])lP2;           // 34816 B overlay (epilogue)

    int g, sub;
    xcd_decode32(blockIdx.x, g, sub);
    int nh = g & 7, kcid = g >> 3, q0 = sub * 128;
    int n = nh >> 2, h = nh & 3;
    const u16* Qh = Q + (long)nh * SEQ * 64;
    const u16* Kh = Km + (long)nh * SEQ * 64;
    const u16* Vh = Vt + (long)nh * 64 * SEQ;
    int t = threadIdx.x, w = t >> 6, lane = t & 63, quad = lane >> 4, l16 = lane & 15;
    const int kblk = kcid * 1024;
    const int dw = w * 16 + l16;     // this wave's V/output d rows

    // Q frags for the full 128-q tile
    bf16x8 Qf[8][2];
    #pragma unroll
    for (int jq = 0; jq < 8; jq++)
        #pragma unroll
        for (int ch = 0; ch < 2; ch++)
            Qf[jq][ch] = *(const bf16x8*)&Qh[(q0 + jq * 16 + l16) * 64 + ch * 32 + quad * 8];

    f32x4 z = {0.f, 0.f, 0.f, 0.f};
    f32x4 acc[8];
    #pragma unroll
    for (int jq = 0; jq < 8; jq++) acc[jq] = z;

// K for stripe I, this wave's 16 k-rows (slab w)
#define LOAD_K(KA, I)                                                         \
    {                                                                         \
        int _kb = kblk + (I) * 64 + w * 16;                                   \
        KA[0] = *(const bf16x8*)&Kh[(_kb + l16) * 64 + quad * 8];             \
        KA[1] = *(const bf16x8*)&Kh[(_kb + l16) * 64 + 32 + quad * 8];        \
    }
// V for stripe I, this wave's 16-d quarter, 2 k-halves of the 64-k stripe
#define LOAD_V(VB, I)                                                         \
    {                                                                         \
        int _kb = kblk + (I) * 64;                                            \
        VB[0] = *(const bf16x8*)&Vh[(long)dw * SEQ + _kb + quad * 8];         \
        VB[1] = *(const bf16x8*)&Vh[(long)dw * SEQ + _kb + 32 + quad * 8];    \
    }
// QK for this wave's 16-k slab -> lP2[B], columns w*16..w*16+15
#define QK_STRIPE(KA, B)                                                      \
    {                                                                         \
        _Pragma("unroll")                                                     \
        for (int jq = 0; jq < 8; jq++) {                                      \
            f32x4 s_ = z;                                                     \
            s_ = __builtin_amdgcn_mfma_f32_16x16x32_bf16(KA[0], Qf[jq][0], s_, 0, 0, 0); \
            s_ = __builtin_amdgcn_mfma_f32_16x16x32_bf16(KA[1], Qf[jq][1], s_, 0, 0, 0); \
            u32 e0 = __float_as_uint(fexp2(s_[0]));                           \
            u32 e1 = __float_as_uint(fexp2(s_[1]));                           \
            u32 e2 = __float_as_uint(fexp2(s_[2]));                           \
            u32 e3 = __float_as_uint(fexp2(s_[3]));                           \
            uint2 pk;                                                         \
            pk.x = __builtin_amdgcn_perm(e1, e0, 0x07060302u);                \
            pk.y = __builtin_amdgcn_perm(e3, e2, 0x07060302u);                \
            *(uint2*)&lP2[B][jq * 16 + l16][w * 16 + quad * 4] = pk;          \
        }                                                                     \
    }
// PV: this wave's 16-d quarter over the full 64-k stripe in buffer B
#define PV_STRIPE(VB, B)                                                      \
    {                                                                         \
        _Pragma("unroll")                                                     \
        for (int ks = 0; ks < 2; ks++) {                                      \
            _Pragma("unroll")                                                 \
            for (int jq = 0; jq < 8; jq++) {                                  \
                bf16x8 pa = *(const bf16x8*)&lP2[B][jq * 16 + l16][ks * 32 + quad * 8]; \
                acc[jq] = __builtin_amdgcn_mfma_f32_16x16x32_bf16(pa, VB[ks], acc[jq], 0, 0, 0); \
            }                                                                 \
        }                                                                     \
    }

    bf16x8 kA0[2], kA1[2], vb0[2], vb1[2];
    LOAD_K(kA0, 0)
    LOAD_V(vb0, 0)
    LOAD_K(kA1, 1)
    LOAD_V(vb1, 1)

    QK_STRIPE(kA0, 0)
    __syncthreads();
    for (int it = 0; it < 7; it++) {
        int i = it * 2;
        // stripe i (buf0) PV; QK(i+1)->buf1 first
        QK_STRIPE(kA1, 1)
        LOAD_K(kA0, i + 2)
        PV_STRIPE(vb0, 0)
        LOAD_V(vb0, i + 2)
        __syncthreads();
        // stripe i+1 (buf1) PV; QK(i+2)->buf0
        QK_STRIPE(kA0, 0)
        LOAD_K(kA1, i + 3)
        PV_STRIPE(vb1, 1)
        LOAD_V(vb1, i + 3)
        __syncthreads();
    }
    // stripe 15 QK -> buf1; stripe 14 PV <- buf0
    QK_STRIPE(kA1, 1)
    PV_STRIPE(vb0, 0)
    __syncthreads();
    // stripe 15 PV <- buf1
    PV_STRIPE(vb1, 1)

#undef LOAD_K
#undef LOAD_V
#undef QK_STRIPE
#undef PV_STRIPE

    // red overlays BOTH P buffers -> barrier before overwrite
    __syncthreads();
    #pragma unroll
    for (int jq = 0; jq < 8; jq++)
        #pragma unroll
        for (int r = 0; r < 4; r++)
            red[jq * 16 + quad * 4 + r][dw] = acc[jq][r];
    __syncthreads();
    float* dst = acat2 + (long)kcid * 8192 * 256;
    #pragma unroll
    for (int p = 0; p < 8; p++) {
        int row = p * 16 + (t >> 4);
        int ch = (t & 15) * 4;
        float4 o = *(float4*)&red[row][ch];
        *(float4*)&dst[((long)n * SEQ + q0 + row) * 256 + h * 64 + ch] = o;
    }
}

// ---------------------------------------------------------------------------
// Fused tail: LN2 + MLP + residual + transposed store (R12-proven).  R22:
// sums 4 acat2 partials.
// ---------------------------------------------------------------------------
__global__ __launch_bounds__(256) void k_tail(const float* __restrict__ x,
                                              const float* __restrict__ acat2,
                                              const float* __restrict__ lnw,
                                              const float* __restrict__ lnb,
                                              const u16* __restrict__ W1t,
                                              const float* __restrict__ b1v,
                                              const u16* __restrict__ W2t,
                                              const float* __restrict__ b2v,
                                              float* __restrict__ out)
{
    __shared__ __align__(16) unsigned char smem[16448];  // tile fp32 / lT u16
    float (*tile)[257] = (float(*)[257])smem;            // [16][257]
    u16 (*lT)[264] = (u16(*)[264])smem;                  // [16][264] overlay
    __shared__ float aF[16][257];                        // folded acat cache
    __shared__ float mu[16], rs[16];
    __shared__ __align__(16) u16 lH[16][264];

    const long STRIDE = (long)8192 * 256;
    int m0 = blockIdx.x * 16;
    int n = m0 >> 12, s0 = m0 & 4095;
    int t = threadIdx.x, w = t >> 6, lane = t & 63, quad = lane >> 4, l16 = lane & 15;

    {
        int sl = t & 15, cg = t >> 4;
        for (int cc = 0; cc < 256; cc += 16) {
            int c = cc + cg;
            tile[sl][c] = x[(n * 256 + c) * SEQ + s0 + sl];
        }
    }
    __syncthreads();
    for (int s = 0; s < 16; s++) {
        long idx = (long)(m0 + s) * 256 + t;
        float a = acat2[idx] + acat2[idx + STRIDE]
                + acat2[idx + 2 * STRIDE] + acat2[idx + 3 * STRIDE];
        aF[s][t] = a;
        tile[s][t] += a;
    }
    __syncthreads();
    {
        int l = t & 63;
        for (int rr = 0; rr < 4; rr++) {
            int s = w * 4 + rr;
            float a0 = tile[s][l], a1 = tile[s][l + 64], a2 = tile[s][l + 128], a3 = tile[s][l + 192];
            float sm = a0 + a1 + a2 + a3;
            float sq = a0 * a0 + a1 * a1 + a2 * a2 + a3 * a3;
            for (int off = 32; off; off >>= 1) { sm += __shfl_xor(sm, off); sq += __shfl_xor(sq, off); }
            if (l == 0) {
                float m = sm * (1.f / 256.f);
                mu[s] = m;
                rs[s] = rsqrtf(sq * (1.f / 256.f) - m * m + 1e-5f);
            }
        }
    }
    __syncthreads();
    {
        float ww = lnw[t], bb = lnb[t];
        for (int s = 0; s < 16; s++)
            lH[s][t] = f2bf((tile[s][t] - mu[s]) * rs[s] * ww + bb);
    }
    __syncthreads();

    f32x4 z = {0.f, 0.f, 0.f, 0.f};
    f32x4 acc1[4];
    #pragma unroll
    for (int js = 0; js < 4; js++) acc1[js] = z;
    #pragma unroll
    for (int kc = 0; kc < 8; kc++) {
        bf16x8 b = *(const bf16x8*)&lH[l16][kc * 32 + quad * 8];
        #pragma unroll
        for (int js = 0; js < 4; js++) {
            bf16x8 a = *(const bf16x8*)&W1t[(long)(w * 64 + js * 16 + l16) * 256 + kc * 32 + quad * 8];
            acc1[js] = __builtin_amdgcn_mfma_f32_16x16x32_bf16(a, b, acc1[js], 0, 0, 0);
        }
    }
    #pragma unroll
    for (int js = 0; js < 4; js++) {
        u32 e[4];
        #pragma unroll
        for (int r = 0; r < 4; r++) {
            int j = w * 64 + js * 16 + quad * 4 + r;
            float v = acc1[js][r] + b1v[j];
            float g = 0.5f * v * (1.f + erff(v * 0.70710678118f));
            u32 u = __float_as_uint(g);
            e[r] = u + 0x7fffu + ((u >> 16) & 1u);
        }
        uint2 pk;
        pk.x = __builtin_amdgcn_perm(e[1], e[0], 0x07060302u);
        pk.y = __builtin_amdgcn_perm(e[3], e[2], 0x07060302u);
        *(uint2*)&lT[l16][w * 64 + js * 16 + quad * 4] = pk;
    }
    __syncthreads();
    f32x4 acc2[4];
    #pragma unroll
    for (int cs = 0; cs < 4; cs++) acc2[cs] = z;
    #pragma unroll
    for (int kc = 0; kc < 8; kc++) {
        bf16x8 pa = *(const bf16x8*)&lT[l16][kc * 32 + quad * 8];
        #pragma unroll
        for (int cs = 0; cs < 4; cs++) {
            bf16x8 wb = *(const bf16x8*)&W2t[(long)(w * 64 + cs * 16 + l16) * 256 + kc * 32 + quad * 8];
            acc2[cs] = __builtin_amdgcn_mfma_f32_16x16x32_bf16(pa, wb, acc2[cs], 0, 0, 0);
        }
    }
    #pragma unroll
    for (int cs = 0; cs < 4; cs++) {
        int c = w * 64 + cs * 16 + l16;
        float bj = b2v[c];
        float vv[4];
        #pragma unroll
        for (int r = 0; r < 4; r++)
            vv[r] = acc2[cs][r] + bj + aF[quad * 4 + r][c];
        float4 o = make_float4(vv[0], vv[1], vv[2], vv[3]);
        *(float4*)&out[((long)n * 256 + c) * SEQ + s0 + quad * 4] = o;
    }
}

// ---------------------------------------------------------------------------
extern "C" void kernel_launch(void* const* d_in, const int* in_sizes, int n_in,
                              void* d_out, int out_size, void* d_ws, size_t ws_size,
                              hipStream_t stream) {
    const float* x    = (const float*)d_in[0];
    const float* ln1w = (const float*)d_in[1];
    const float* ln1b = (const float*)d_in[2];
    const float* WQ   = (const float*)d_in[3];
    const float* WK   = (const float*)d_in[4];
    const float* WV   = (const float*)d_in[5];
    const float* ln2w = (const float*)d_in[6];
    const float* ln2b = (const float*)d_in[7];
    const float* W1   = (const float*)d_in[8];
    const float* b1   = (const float*)d_in[9];
    const float* W2   = (const float*)d_in[10];
    const float* b2   = (const float*)d_in[11];
    float* out = (float*)d_out;

    char* p = (char*)d_ws;
    u16* norm   = (u16*)p;   p += (size_t)8192 * 256 * 2;
    u16* BtQKV  = (u16*)p;   p += (size_t)768 * 256 * 2;
    u16* W1t    = (u16*)p;   p += (size_t)256 * 256 * 2;
    u16* W2t    = (u16*)p;   p += (size_t)256 * 256 * 2;
    u16* Qb     = (u16*)p;   p += (size_t)NHT * SEQ * 64 * 2;
    u16* Kb     = (u16*)p;   p += (size_t)NHT * SEQ * 64 * 2;
    u16* VtT    = (u16*)p;   p += (size_t)NHT * SEQ * 64 * 2;
    float* D2   = (float*)p; p += (size_t)4 * NHT * SEQ * 4;
    float* acat2= (float*)p; p += (size_t)4 * 8192 * 256 * 4;
    // Vf (f32 transposed V, 8.4 MB) overlays acat2: qkv writes it, vdiv
    // consumes it, THEN pass2 overwrites acat2 — stream-ordered, no extra ws.
    float* Vf   = acat2;

    k_prep<<<1536, 256, 0, stream>>>(x, ln1w, ln1b, WQ, WK, WV, W1, W2,
                                     norm, BtQKV, W1t, W2t);
    k_qkv<<<dim3(128, 6), 256, 0, stream>>>(norm, BtQKV, Qb, Kb, Vf);
    k_pass1<<<1024, 256, 0, stream>>>(Qb, Kb, D2);
    k_vdiv<<<512, 256, 0, stream>>>(Vf, D2, VtT);
    k_pass2<<<1024, 256, 0, stream>>>(Qb, Kb, VtT, acat2);
    k_tail<<<512, 256, 0, stream>>>(x, acat2, ln2w, ln2b, W1t, b1, W2t, b2, out);
}

// Round 12
// 230.261 us; speedup vs baseline: 1.3177x; 1.3177x over previous
//
#include <hip/hip_runtime.h>
#include <math.h>

#define SEQ 4096
#define CH  256
#define NHT 8      // N * HEADS
#define DHD 64

// Q is pre-scaled by log2(e)/64 at projection time, so both attention passes
// compute exp2(S) with zero multiplies.
#define QSCALE 0.0225421092f

using bf16x8 = __attribute__((ext_vector_type(8))) short;
using f32x4  = __attribute__((ext_vector_type(4))) float;
typedef unsigned short u16;
typedef unsigned int   u32;

__device__ __forceinline__ u16 f2bf(float f) {
    u32 u = __float_as_uint(f);
    u = (u + 0x7fffu + ((u >> 16) & 1u)) >> 16;
    return (u16)u;
}
__device__ __forceinline__ float bf2f(u16 h) {
    return __uint_as_float(((u32)h) << 16);
}
// raw v_exp_f32 — exp2f without -ffast-math is an OCML call (~8 VALU ops)
__device__ __forceinline__ float fexp2(float x) {
    return __builtin_amdgcn_exp2f(x);
}

// ---------------------------------------------------------------------------
// Prep: weight pack (blocks 0..1279) + LN1 (blocks 1280..1535), one launch.
// ---------------------------------------------------------------------------
__global__ __launch_bounds__(256) void k_prep(const float* __restrict__ x,
                                              const float* __restrict__ ln1w,
                                              const float* __restrict__ ln1b,
                                              const float* __restrict__ WQ,
                                              const float* __restrict__ WK,
                                              const float* __restrict__ WV,
                                              const float* __restrict__ W1,
                                              const float* __restrict__ W2,
                                              u16* __restrict__ norm,
                                              u16* __restrict__ BtQKV,
                                              u16* __restrict__ W1t,
                                              u16* __restrict__ W2t)
{
    __shared__ float tile[32][257];
    __shared__ float mu[32], rs[32];
    int bid = blockIdx.x;
    int t = threadIdx.x;
    if (bid < 1280) {   // ---- pack ----
        int id = bid * 256 + t;
        if (id < 768 * 256) {
            int j = id >> 8, c = id & 255;
            int which = j >> 8, h = (j >> 6) & 3, d = j & 63;
            const float* W = (which == 0) ? WQ : (which == 1) ? WK : WV;
            BtQKV[id] = f2bf(W[(h * 256 + c) * 64 + d]);
        } else if (id < 768 * 256 + 65536) {
            int jj = id - 768 * 256;
            int j = jj >> 8, c = jj & 255;
            W1t[jj] = f2bf(W1[c * 256 + j]);
        } else if (id < 768 * 256 + 2 * 65536) {
            int jj = id - 768 * 256 - 65536;
            int j = jj >> 8, c = jj & 255;
            W2t[jj] = f2bf(W2[c * 256 + j]);
        }
        return;
    }
    // ---- LN1 ----
    int b2i = bid - 1280;
    int n = b2i >> 7, s0 = (b2i & 127) * 32;
    int sl = t & 31, cg = t >> 5;
    for (int cc = 0; cc < 256; cc += 8) {
        int c = cc + cg;
        tile[sl][c] = x[(n * 256 + c) * SEQ + s0 + sl];
    }
    __syncthreads();
    int wv = t >> 6, l = t & 63;
    for (int rr = 0; rr < 8; rr++) {
        int s = wv * 8 + rr;
        float a0 = tile[s][l], a1 = tile[s][l + 64], a2 = tile[s][l + 128], a3 = tile[s][l + 192];
        float sm = a0 + a1 + a2 + a3;
        float sq = a0 * a0 + a1 * a1 + a2 * a2 + a3 * a3;
        for (int off = 32; off; off >>= 1) { sm += __shfl_xor(sm, off); sq += __shfl_xor(sq, off); }
        if (l == 0) {
            float m = sm * (1.f / 256.f);
            mu[s] = m;
            rs[s] = rsqrtf(sq * (1.f / 256.f) - m * m + 1e-5f);
        }
    }
    __syncthreads();
    float ww = ln1w[t], bb = ln1b[t];
    for (int s = 0; s < 32; s++) {
        float v = (tile[s][t] - mu[s]) * rs[s] * ww + bb;
        norm[(n * SEQ + s0 + s) * 256 + t] = f2bf(v);
    }
}

// ---------------------------------------------------------------------------
// QKV projection, barrier-free (R4-proven). Q pre-scaled by QSCALE.
// V written transposed in FP32 (Vf[nh][d][k]); k_vdiv rounds to bf16 once.
// ---------------------------------------------------------------------------
__global__ __launch_bounds__(256) void k_qkv(const u16* __restrict__ norm,
                                             const u16* __restrict__ Bt,
                                             u16* __restrict__ Qo,
                                             u16* __restrict__ Ko,
                                             float* __restrict__ Vfo)
{
    int m0 = blockIdx.x * 64, j0 = blockIdx.y * 128;
    int t = threadIdx.x, w = t >> 6, lane = t & 63, quad = lane >> 4, l16 = lane & 15;
    const u16* Ap = norm + (long)(m0 + w * 16 + l16) * 256;
    const u16* Bp = Bt + (long)j0 * 256;
    f32x4 z = {0.f, 0.f, 0.f, 0.f};
    f32x4 acc[8];
    #pragma unroll
    for (int j = 0; j < 8; j++) acc[j] = z;
    #pragma unroll
    for (int kc = 0; kc < 8; kc++) {
        bf16x8 a = *(const bf16x8*)&Ap[kc * 32 + quad * 8];
        #pragma unroll
        for (int j = 0; j < 8; j++) {
            bf16x8 b = *(const bf16x8*)&Bp[(long)(j * 16 + l16) * 256 + kc * 32 + quad * 8];
            acc[j] = __builtin_amdgcn_mfma_f32_16x16x32_bf16(a, b, acc[j], 0, 0, 0);
        }
    }
    #pragma unroll
    for (int j = 0; j < 8; j++) {
        int col = j0 + j * 16 + l16;
        int which = col >> 8, h = (col >> 6) & 3, d = col & 63;
        int m = m0 + w * 16 + quad * 4;
        int n = m >> 12, s = m & 4095;
        if (which == 2) {
            float4 o = make_float4(acc[j][0], acc[j][1], acc[j][2], acc[j][3]);
            *(float4*)&Vfo[((long)(n * 4 + h) * 64 + d) * SEQ + s] = o;
        } else {
            u16* dst = (which == 0) ? Qo : Ko;
            float sc = (which == 0) ? QSCALE : 1.0f;
            #pragma unroll
            for (int r = 0; r < 4; r++)
                dst[((n * 4 + h) * SEQ + s + r) * 64 + d] = f2bf(acc[j][r] * sc);
        }
    }
}

// ---------------------------------------------------------------------------
// XCD-group swizzles (R16-proven: FETCH 37.5->8.3 MB).
// 1024-block grids: 32 groups x 32 sub-blocks; group g on XCD g>>2.
// ---------------------------------------------------------------------------
__device__ __forceinline__ void xcd_decode32(int s, int& g, int& sub) {
    int xcd = s & 7, m = s >> 3;
    g = xcd * 4 + (m >> 5);
    sub = m & 31;
}

// ---------------------------------------------------------------------------
// Pass 1 (R21-proven): qc=4 grid + __launch_bounds__(256,3).
// ---------------------------------------------------------------------------
__global__ __launch_bounds__(256, 3) void k_pass1(const u16* __restrict__ Q,
                                                  const u16* __restrict__ Km,
                                                  float* __restrict__ D2)
{
    __shared__ float Dred[128];
    int g, sub;
    xcd_decode32(blockIdx.x, g, sub);
    int nh = g & 7, qc = g >> 3, k0 = sub * 128;
    const u16* Qh = Q + (long)nh * SEQ * 64;
    const u16* Kh = Km + (long)nh * SEQ * 64;
    int t = threadIdx.x, w = t >> 6, lane = t & 63, quad = lane >> 4, l16 = lane & 15;
    bf16x8 Kf[8][2];
    #pragma unroll
    for (int i = 0; i < 8; i++) {
        Kf[i][0] = *(const bf16x8*)&Kh[(k0 + i * 16 + l16) * 64 + quad * 8];
        Kf[i][1] = *(const bf16x8*)&Kh[(k0 + i * 16 + l16) * 64 + 32 + quad * 8];
    }
    if (t < 128) Dred[t] = 0.f;
    f32x4 z = {0.f, 0.f, 0.f, 0.f};
    float Dacc[8][4] = {};
    const int qw0 = qc * 1024 + w * 256;

#define P1_LOADQ(B0, B1, ST)                                                  \
    {                                                                         \
        int _q = qw0 + (ST) * 16 + l16;                                       \
        B0 = *(const bf16x8*)&Qh[_q * 64 + quad * 8];                         \
        B1 = *(const bf16x8*)&Qh[_q * 64 + 32 + quad * 8];                    \
    }
#define P1_STEP(B0, B1)                                                       \
    {                                                                         \
        _Pragma("unroll")                                                     \
        for (int i = 0; i < 8; i++) {                                         \
            f32x4 acc = z;                                                    \
            acc = __builtin_amdgcn_mfma_f32_16x16x32_bf16(Kf[i][0], B0, acc, 0, 0, 0); \
            acc = __builtin_amdgcn_mfma_f32_16x16x32_bf16(Kf[i][1], B1, acc, 0, 0, 0); \
            _Pragma("unroll")                                                 \
            for (int r = 0; r < 4; r++) Dacc[i][r] += fexp2(acc[r]);          \
        }                                                                     \
    }

    bf16x8 qa0, qa1, qb0, qb1;
    P1_LOADQ(qa0, qa1, 0)
    P1_LOADQ(qb0, qb1, 1)
    for (int st = 0; st < 16; st += 2) {
        P1_STEP(qa0, qa1)
        if (st + 2 < 16) { P1_LOADQ(qa0, qa1, st + 2) }
        P1_STEP(qb0, qb1)
        if (st + 3 < 16) { P1_LOADQ(qb0, qb1, st + 3) }
    }
#undef P1_LOADQ
#undef P1_STEP

    #pragma unroll
    for (int i = 0; i < 8; i++)
        #pragma unroll
        for (int r = 0; r < 4; r++) {
            float v = Dacc[i][r];
            v += __shfl_xor(v, 1); v += __shfl_xor(v, 2);
            v += __shfl_xor(v, 4); v += __shfl_xor(v, 8);
            Dacc[i][r] = v;
        }
    __syncthreads();
    if (l16 == 0) {
        #pragma unroll
        for (int i = 0; i < 8; i++)
            #pragma unroll
            for (int r = 0; r < 4; r++)
                atomicAdd(&Dred[i * 16 + quad * 4 + r], Dacc[i][r]);
    }
    __syncthreads();
    if (t < 128) D2[((long)(qc * NHT + nh)) * SEQ + k0 + t] = Dred[t];
}

// ---------------------------------------------------------------------------
// V pre-scale (R16-proven): z[q,k] = exp(S)/D[k], so fold 1/D into V once.
// D2 has 4 qc-partials.
// ---------------------------------------------------------------------------
__global__ __launch_bounds__(256) void k_vdiv(const float* __restrict__ Vf,
                                              const float* __restrict__ D2,
                                              u16* __restrict__ Vto)
{
    int b = blockIdx.x;
    int nh = b >> 6, d = b & 63;
    const long QS = (long)NHT * SEQ;
    const float* Dp = D2 + (long)nh * SEQ;
    const float* src = Vf + ((long)nh * 64 + d) * SEQ;
    u16* dst = Vto + ((long)nh * 64 + d) * SEQ;
    int t = threadIdx.x;
    #pragma unroll
    for (int half = 0; half < 2; half++) {
        int k = half * 2048 + t * 8;
        float o[8];
        #pragma unroll
        for (int e = 0; e < 8; e++) {
            float dsum = Dp[k + e] + Dp[QS + k + e] + Dp[2 * QS + k + e] + Dp[3 * QS + k + e];
            o[e] = src[k + e] / dsum;
        }
        uint4 pk;
        pk.x = (u32)f2bf(o[0]) | ((u32)f2bf(o[1]) << 16);
        pk.y = (u32)f2bf(o[2]) | ((u32)f2bf(o[3]) << 16);
        pk.z = (u32)f2bf(o[4]) | ((u32)f2bf(o[5]) << 16);
        pk.w = (u32)f2bf(o[6]) | ((u32)f2bf(o[7]) << 16);
        *(uint4*)&dst[k] = pk;
    }
}

// ---------------------------------------------------------------------------
// Pass 2, R24: kcid=4 grid (R22) with __launch_bounds__(256,3) (R21's
// proven-no-spill bound).  R22's (256,4) capped regs at 128 < ~140 live
// (Qf 64 + acc 32 + kA/vb 32 + addr) -> Qf spilled, WRITE_SIZE 256 MB,
// 129 µs.  (256,3) caps ~170: R21 measured 76 VGPR + 32 acc, no spill.
// The 1024-block grid supplies 4 blocks/CU of work; residency settles at
// the reg-limited 3/CU (vs R21's grid-limited 2).  LDS 34816 x 3 fits.
// acat2 keeps 4 partials (tail sums 4).
// ---------------------------------------------------------------------------
__global__ __launch_bounds__(256, 3) void k_pass2(const u16* __restrict__ Q,
                                                  const u16* __restrict__ Km,
                                                  const u16* __restrict__ Vt,
                                                  float* __restrict__ acat2)
{
    __shared__ __align__(16) u16 lP2[2][128][68];   // 34816 B
    float (*red)[68] = (float(*)[68])lP2;           // 34816 B overlay (epilogue)

    int g, sub;
    xcd_decode32(blockIdx.x, g, sub);
    int nh = g & 7, kcid = g >> 3, q0 = sub * 128;
    int n = nh >> 2, h = nh & 3;
    const u16* Qh = Q + (long)nh * SEQ * 64;
    const u16* Kh = Km + (long)nh * SEQ * 64;
    const u16* Vh = Vt + (long)nh * 64 * SEQ;
    int t = threadIdx.x, w = t >> 6, lane = t & 63, quad = lane >> 4, l16 = lane & 15;
    const int kblk = kcid * 1024;
    const int dw = w * 16 + l16;     // this wave's V/output d rows

    // Q frags for the full 128-q tile
    bf16x8 Qf[8][2];
    #pragma unroll
    for (int jq = 0; jq < 8; jq++)
        #pragma unroll
        for (int ch = 0; ch < 2; ch++)
            Qf[jq][ch] = *(const bf16x8*)&Qh[(q0 + jq * 16 + l16) * 64 + ch * 32 + quad * 8];

    f32x4 z = {0.f, 0.f, 0.f, 0.f};
    f32x4 acc[8];
    #pragma unroll
    for (int jq = 0; jq < 8; jq++) acc[jq] = z;

// K for stripe I, this wave's 16 k-rows (slab w)
#define LOAD_K(KA, I)                                                         \
    {                                                                         \
        int _kb = kblk + (I) * 64 + w * 16;                                   \
        KA[0] = *(const bf16x8*)&Kh[(_kb + l16) * 64 + quad * 8];             \
        KA[1] = *(const bf16x8*)&Kh[(_kb + l16) * 64 + 32 + quad * 8];        \
    }
// V for stripe I, this wave's 16-d quarter, 2 k-halves of the 64-k stripe
#define LOAD_V(VB, I)                                                         \
    {                                                                         \
        int _kb = kblk + (I) * 64;                                            \
        VB[0] = *(const bf16x8*)&Vh[(long)dw * SEQ + _kb + quad * 8];         \
        VB[1] = *(const bf16x8*)&Vh[(long)dw * SEQ + _kb + 32 + quad * 8];    \
    }
// QK for this wave's 16-k slab -> lP2[B], columns w*16..w*16+15
#define QK_STRIPE(KA, B)                                                      \
    {                                                                         \
        _Pragma("unroll")                                                     \
        for (int jq = 0; jq < 8; jq++) {                                      \
            f32x4 s_ = z;                                                     \
            s_ = __builtin_amdgcn_mfma_f32_16x16x32_bf16(KA[0], Qf[jq][0], s_, 0, 0, 0); \
            s_ = __builtin_amdgcn_mfma_f32_16x16x32_bf16(KA[1], Qf[jq][1], s_, 0, 0, 0); \
            u32 e0 = __float_as_uint(fexp2(s_[0]));                           \
            u32 e1 = __float_as_uint(fexp2(s_[1]));                           \
            u32 e2 = __float_as_uint(fexp2(s_[2]));                           \
            u32 e3 = __float_as_uint(fexp2(s_[3]));                           \
            uint2 pk;                                                         \
            pk.x = __builtin_amdgcn_perm(e1, e0, 0x07060302u);                \
            pk.y = __builtin_amdgcn_perm(e3, e2, 0x07060302u);                \
            *(uint2*)&lP2[B][jq * 16 + l16][w * 16 + quad * 4] = pk;          \
        }                                                                     \
    }
// PV: this wave's 16-d quarter over the full 64-k stripe in buffer B
#define PV_STRIPE(VB, B)                                                      \
    {                                                                         \
        _Pragma("unroll")                                                     \
        for (int ks = 0; ks < 2; ks++) {                                      \
            _Pragma("unroll")                                                 \
            for (int jq = 0; jq < 8; jq++) {                                  \
                bf16x8 pa = *(const bf16x8*)&lP2[B][jq * 16 + l16][ks * 32 + quad * 8]; \
                acc[jq] = __builtin_amdgcn_mfma_f32_16x16x32_bf16(pa, VB[ks], acc[jq], 0, 0, 0); \
            }                                                                 \
        }                                                                     \
    }

    bf16x8 kA0[2], kA1[2], vb0[2], vb1[2];
    LOAD_K(kA0, 0)
    LOAD_V(vb0, 0)
    LOAD_K(kA1, 1)
    LOAD_V(vb1, 1)

    QK_STRIPE(kA0, 0)
    __syncthreads();
    for (int it = 0; it < 7; it++) {
        int i = it * 2;
        // stripe i (buf0) PV; QK(i+1)->buf1 first
        QK_STRIPE(kA1, 1)
        LOAD_K(kA0, i + 2)
        PV_STRIPE(vb0, 0)
        LOAD_V(vb0, i + 2)
        __syncthreads();
        // stripe i+1 (buf1) PV; QK(i+2)->buf0
        QK_STRIPE(kA0, 0)
        LOAD_K(kA1, i + 3)
        PV_STRIPE(vb1, 1)
        LOAD_V(vb1, i + 3)
        __syncthreads();
    }
    // stripe 15 QK -> buf1; stripe 14 PV <- buf0
    QK_STRIPE(kA1, 1)
    PV_STRIPE(vb0, 0)
    __syncthreads();
    // stripe 15 PV <- buf1
    PV_STRIPE(vb1, 1)

#undef LOAD_K
#undef LOAD_V
#undef QK_STRIPE
#undef PV_STRIPE

    // red overlays BOTH P buffers -> barrier before overwrite
    __syncthreads();
    #pragma unroll
    for (int jq = 0; jq < 8; jq++)
        #pragma unroll
        for (int r = 0; r < 4; r++)
            red[jq * 16 + quad * 4 + r][dw] = acc[jq][r];
    __syncthreads();
    float* dst = acat2 + (long)kcid * 8192 * 256;
    #pragma unroll
    for (int p = 0; p < 8; p++) {
        int row = p * 16 + (t >> 4);
        int ch = (t & 15) * 4;
        float4 o = *(float4*)&red[row][ch];
        *(float4*)&dst[((long)n * SEQ + q0 + row) * 256 + h * 64 + ch] = o;
    }
}

// ---------------------------------------------------------------------------
// Fused tail: LN2 + MLP + residual + transposed store (R12-proven).
// Sums 4 acat2 partials.
// ---------------------------------------------------------------------------
__global__ __launch_bounds__(256) void k_tail(const float* __restrict__ x,
                                              const float* __restrict__ acat2,
                                              const float* __restrict__ lnw,
                                              const float* __restrict__ lnb,
                                              const u16* __restrict__ W1t,
                                              const float* __restrict__ b1v,
                                              const u16* __restrict__ W2t,
                                              const float* __restrict__ b2v,
                                              float* __restrict__ out)
{
    __shared__ __align__(16) unsigned char smem[16448];  // tile fp32 / lT u16
    float (*tile)[257] = (float(*)[257])smem;            // [16][257]
    u16 (*lT)[264] = (u16(*)[264])smem;                  // [16][264] overlay
    __shared__ float aF[16][257];                        // folded acat cache
    __shared__ float mu[16], rs[16];
    __shared__ __align__(16) u16 lH[16][264];

    const long STRIDE = (long)8192 * 256;
    int m0 = blockIdx.x * 16;
    int n = m0 >> 12, s0 = m0 & 4095;
    int t = threadIdx.x, w = t >> 6, lane = t & 63, quad = lane >> 4, l16 = lane & 15;

    {
        int sl = t & 15, cg = t >> 4;
        for (int cc = 0; cc < 256; cc += 16) {
            int c = cc + cg;
            tile[sl][c] = x[(n * 256 + c) * SEQ + s0 + sl];
        }
    }
    __syncthreads();
    for (int s = 0; s < 16; s++) {
        long idx = (long)(m0 + s) * 256 + t;
        float a = acat2[idx] + acat2[idx + STRIDE]
                + acat2[idx + 2 * STRIDE] + acat2[idx + 3 * STRIDE];
        aF[s][t] = a;
        tile[s][t] += a;
    }
    __syncthreads();
    {
        int l = t & 63;
        for (int rr = 0; rr < 4; rr++) {
            int s = w * 4 + rr;
            float a0 = tile[s][l], a1 = tile[s][l + 64], a2 = tile[s][l + 128], a3 = tile[s][l + 192];
            float sm = a0 + a1 + a2 + a3;
            float sq = a0 * a0 + a1 * a1 + a2 * a2 + a3 * a3;
            for (int off = 32; off; off >>= 1) { sm += __shfl_xor(sm, off); sq += __shfl_xor(sq, off); }
            if (l == 0) {
                float m = sm * (1.f / 256.f);
                mu[s] = m;
                rs[s] = rsqrtf(sq * (1.f / 256.f) - m * m + 1e-5f);
            }
        }
    }
    __syncthreads();
    {
        float ww = lnw[t], bb = lnb[t];
        for (int s = 0; s < 16; s++)
            lH[s][t] = f2bf((tile[s][t] - mu[s]) * rs[s] * ww + bb);
    }
    __syncthreads();

    f32x4 z = {0.f, 0.f, 0.f, 0.f};
    f32x4 acc1[4];
    #pragma unroll
    for (int js = 0; js < 4; js++) acc1[js] = z;
    #pragma unroll
    for (int kc = 0; kc < 8; kc++) {
        bf16x8 b = *(const bf16x8*)&lH[l16][kc * 32 + quad * 8];
        #pragma unroll
        for (int js = 0; js < 4; js++) {
            bf16x8 a = *(const bf16x8*)&W1t[(long)(w * 64 + js * 16 + l16) * 256 + kc * 32 + quad * 8];
            acc1[js] = __builtin_amdgcn_mfma_f32_16x16x32_bf16(a, b, acc1[js], 0, 0, 0);
        }
    }
    #pragma unroll
    for (int js = 0; js < 4; js++) {
        u32 e[4];
        #pragma unroll
        for (int r = 0; r < 4; r++) {
            int j = w * 64 + js * 16 + quad * 4 + r;
            float v = acc1[js][r] + b1v[j];
            float g = 0.5f * v * (1.f + erff(v * 0.70710678118f));
            u32 u = __float_as_uint(g);
            e[r] = u + 0x7fffu + ((u >> 16) & 1u);
        }
        uint2 pk;
        pk.x = __builtin_amdgcn_perm(e[1], e[0], 0x07060302u);
        pk.y = __builtin_amdgcn_perm(e[3], e[2], 0x07060302u);
        *(uint2*)&lT[l16][w * 64 + js * 16 + quad * 4] = pk;
    }
    __syncthreads();
    f32x4 acc2[4];
    #pragma unroll
    for (int cs = 0; cs < 4; cs++) acc2[cs] = z;
    #pragma unroll
    for (int kc = 0; kc < 8; kc++) {
        bf16x8 pa = *(const bf16x8*)&lT[l16][kc * 32 + quad * 8];
        #pragma unroll
        for (int cs = 0; cs < 4; cs++) {
            bf16x8 wb = *(const bf16x8*)&W2t[(long)(w * 64 + cs * 16 + l16) * 256 + kc * 32 + quad * 8];
            acc2[cs] = __builtin_amdgcn_mfma_f32_16x16x32_bf16(pa, wb, acc2[cs], 0, 0, 0);
        }
    }
    #pragma unroll
    for (int cs = 0; cs < 4; cs++) {
        int c = w * 64 + cs * 16 + l16;
        float bj = b2v[c];
        float vv[4];
        #pragma unroll
        for (int r = 0; r < 4; r++)
            vv[r] = acc2[cs][r] + bj + aF[quad * 4 + r][c];
        float4 o = make_float4(vv[0], vv[1], vv[2], vv[3]);
        *(float4*)&out[((long)n * 256 + c) * SEQ + s0 + quad * 4] = o;
    }
}

// ---------------------------------------------------------------------------
extern "C" void kernel_launch(void* const* d_in, const int* in_sizes, int n_in,
                              void* d_out, int out_size, void* d_ws, size_t ws_size,
                              hipStream_t stream) {
    const float* x    = (const float*)d_in[0];
    const float* ln1w = (const float*)d_in[1];
    const float* ln1b = (const float*)d_in[2];
    const float* WQ   = (const float*)d_in[3];
    const float* WK   = (const float*)d_in[4];
    const float* WV   = (const float*)d_in[5];
    const float* ln2w = (const float*)d_in[6];
    const float* ln2b = (const float*)d_in[7];
    const float* W1   = (const float*)d_in[8];
    const float* b1   = (const float*)d_in[9];
    const float* W2   = (const float*)d_in[10];
    const float* b2   = (const float*)d_in[11];
    float* out = (float*)d_out;

    char* p = (char*)d_ws;
    u16* norm   = (u16*)p;   p += (size_t)8192 * 256 * 2;
    u16* BtQKV  = (u16*)p;   p += (size_t)768 * 256 * 2;
    u16* W1t    = (u16*)p;   p += (size_t)256 * 256 * 2;
    u16* W2t    = (u16*)p;   p += (size_t)256 * 256 * 2;
    u16* Qb     = (u16*)p;   p += (size_t)NHT * SEQ * 64 * 2;
    u16* Kb     = (u16*)p;   p += (size_t)NHT * SEQ * 64 * 2;
    u16* VtT    = (u16*)p;   p += (size_t)NHT * SEQ * 64 * 2;
    float* D2   = (float*)p; p += (size_t)4 * NHT * SEQ * 4;
    float* acat2= (float*)p; p += (size_t)4 * 8192 * 256 * 4;
    // Vf (f32 transposed V, 8.4 MB) overlays acat2: qkv writes it, vdiv
    // consumes it, THEN pass2 overwrites acat2 — stream-ordered, no extra ws.
    float* Vf   = acat2;

    k_prep<<<1536, 256, 0, stream>>>(x, ln1w, ln1b, WQ, WK, WV, W1, W2,
                                     norm, BtQKV, W1t, W2t);
    k_qkv<<<dim3(128, 6), 256, 0, stream>>>(norm, BtQKV, Qb, Kb, Vf);
    k_pass1<<<1024, 256, 0, stream>>>(Qb, Kb, D2);
    k_vdiv<<<512, 256, 0, stream>>>(Vf, D2, VtT);
    k_pass2<<<1024, 256, 0, stream>>>(Qb, Kb, VtT, acat2);
    k_tail<<<512, 256, 0, stream>>>(x, acat2, ln2w, ln2b, W1t, b1, W2t, b2, out);
}

// Round 13
// 227.971 us; speedup vs baseline: 1.3309x; 1.0100x over previous
//
#include <hip/hip_runtime.h>
#include <math.h>

#define SEQ 4096
#define CH  256
#define NHT 8      // N * HEADS
#define DHD 64

// Q is pre-scaled by log2(e)/64 at projection time, so both attention passes
// compute exp2(S) with zero multiplies.
#define QSCALE 0.0225421092f

using bf16x8 = __attribute__((ext_vector_type(8))) short;
using f32x4  = __attribute__((ext_vector_type(4))) float;
typedef unsigned short u16;
typedef unsigned int   u32;

__device__ __forceinline__ u16 f2bf(float f) {
    u32 u = __float_as_uint(f);
    u = (u + 0x7fffu + ((u >> 16) & 1u)) >> 16;
    return (u16)u;
}
__device__ __forceinline__ float bf2f(u16 h) {
    return __uint_as_float(((u32)h) << 16);
}
// raw v_exp_f32 — exp2f without -ffast-math is an OCML call (~8 VALU ops)
__device__ __forceinline__ float fexp2(float x) {
    return __builtin_amdgcn_exp2f(x);
}

// ---------------------------------------------------------------------------
// Prep: weight pack (blocks 0..1279) + LN1 (blocks 1280..1535), one launch.
// ---------------------------------------------------------------------------
__global__ __launch_bounds__(256) void k_prep(const float* __restrict__ x,
                                              const float* __restrict__ ln1w,
                                              const float* __restrict__ ln1b,
                                              const float* __restrict__ WQ,
                                              const float* __restrict__ WK,
                                              const float* __restrict__ WV,
                                              const float* __restrict__ W1,
                                              const float* __restrict__ W2,
                                              u16* __restrict__ norm,
                                              u16* __restrict__ BtQKV,
                                              u16* __restrict__ W1t,
                                              u16* __restrict__ W2t)
{
    __shared__ float tile[32][257];
    __shared__ float mu[32], rs[32];
    int bid = blockIdx.x;
    int t = threadIdx.x;
    if (bid < 1280) {   // ---- pack ----
        int id = bid * 256 + t;
        if (id < 768 * 256) {
            int j = id >> 8, c = id & 255;
            int which = j >> 8, h = (j >> 6) & 3, d = j & 63;
            const float* W = (which == 0) ? WQ : (which == 1) ? WK : WV;
            BtQKV[id] = f2bf(W[(h * 256 + c) * 64 + d]);
        } else if (id < 768 * 256 + 65536) {
            int jj = id - 768 * 256;
            int j = jj >> 8, c = jj & 255;
            W1t[jj] = f2bf(W1[c * 256 + j]);
        } else if (id < 768 * 256 + 2 * 65536) {
            int jj = id - 768 * 256 - 65536;
            int j = jj >> 8, c = jj & 255;
            W2t[jj] = f2bf(W2[c * 256 + j]);
        }
        return;
    }
    // ---- LN1 ----
    int b2i = bid - 1280;
    int n = b2i >> 7, s0 = (b2i & 127) * 32;
    int sl = t & 31, cg = t >> 5;
    for (int cc = 0; cc < 256; cc += 8) {
        int c = cc + cg;
        tile[sl][c] = x[(n * 256 + c) * SEQ + s0 + sl];
    }
    __syncthreads();
    int wv = t >> 6, l = t & 63;
    for (int rr = 0; rr < 8; rr++) {
        int s = wv * 8 + rr;
        float a0 = tile[s][l], a1 = tile[s][l + 64], a2 = tile[s][l + 128], a3 = tile[s][l + 192];
        float sm = a0 + a1 + a2 + a3;
        float sq = a0 * a0 + a1 * a1 + a2 * a2 + a3 * a3;
        for (int off = 32; off; off >>= 1) { sm += __shfl_xor(sm, off); sq += __shfl_xor(sq, off); }
        if (l == 0) {
            float m = sm * (1.f / 256.f);
            mu[s] = m;
            rs[s] = rsqrtf(sq * (1.f / 256.f) - m * m + 1e-5f);
        }
    }
    __syncthreads();
    float ww = ln1w[t], bb = ln1b[t];
    for (int s = 0; s < 32; s++) {
        float v = (tile[s][t] - mu[s]) * rs[s] * ww + bb;
        norm[(n * SEQ + s0 + s) * 256 + t] = f2bf(v);
    }
}

// ---------------------------------------------------------------------------
// QKV projection, barrier-free (R4-proven). Q pre-scaled by QSCALE.
// V written transposed in FP32 (Vf[nh][d][k]); k_vdiv rounds to bf16 once.
// ---------------------------------------------------------------------------
__global__ __launch_bounds__(256) void k_qkv(const u16* __restrict__ norm,
                                             const u16* __restrict__ Bt,
                                             u16* __restrict__ Qo,
                                             u16* __restrict__ Ko,
                                             float* __restrict__ Vfo)
{
    int m0 = blockIdx.x * 64, j0 = blockIdx.y * 128;
    int t = threadIdx.x, w = t >> 6, lane = t & 63, quad = lane >> 4, l16 = lane & 15;
    const u16* Ap = norm + (long)(m0 + w * 16 + l16) * 256;
    const u16* Bp = Bt + (long)j0 * 256;
    f32x4 z = {0.f, 0.f, 0.f, 0.f};
    f32x4 acc[8];
    #pragma unroll
    for (int j = 0; j < 8; j++) acc[j] = z;
    #pragma unroll
    for (int kc = 0; kc < 8; kc++) {
        bf16x8 a = *(const bf16x8*)&Ap[kc * 32 + quad * 8];
        #pragma unroll
        for (int j = 0; j < 8; j++) {
            bf16x8 b = *(const bf16x8*)&Bp[(long)(j * 16 + l16) * 256 + kc * 32 + quad * 8];
            acc[j] = __builtin_amdgcn_mfma_f32_16x16x32_bf16(a, b, acc[j], 0, 0, 0);
        }
    }
    #pragma unroll
    for (int j = 0; j < 8; j++) {
        int col = j0 + j * 16 + l16;
        int which = col >> 8, h = (col >> 6) & 3, d = col & 63;
        int m = m0 + w * 16 + quad * 4;
        int n = m >> 12, s = m & 4095;
        if (which == 2) {
            float4 o = make_float4(acc[j][0], acc[j][1], acc[j][2], acc[j][3]);
            *(float4*)&Vfo[((long)(n * 4 + h) * 64 + d) * SEQ + s] = o;
        } else {
            u16* dst = (which == 0) ? Qo : Ko;
            float sc = (which == 0) ? QSCALE : 1.0f;
            #pragma unroll
            for (int r = 0; r < 4; r++)
                dst[((n * 4 + h) * SEQ + s + r) * 64 + d] = f2bf(acc[j][r] * sc);
        }
    }
}

// ---------------------------------------------------------------------------
// XCD-group swizzles (R16-proven: FETCH 37.5->8.3 MB).
// pass2 (512 blocks): 16 groups x 32 subs; group g on XCD g>>1.
// pass1 (1024 blocks, R25): 16 groups (nh x qc) x 64 k-subs; group g on
// XCD g>>1 (2 groups/XCD; L2 footprint K 512K + Q-half 256K per group).
// ---------------------------------------------------------------------------
__device__ __forceinline__ void xcd_decode(int s, int& g, int& sub) {
    int xcd = s & 7, m = s >> 3;
    g = xcd * 2 + (m >> 5);
    sub = m & 31;
}
__device__ __forceinline__ void xcd_decode64(int s, int& g, int& sub) {
    int xcd = s & 7, m = s >> 3;      // m in 0..127
    g = xcd * 2 + (m >> 6);           // 16 groups
    sub = m & 63;                     // 64 k-sub-blocks
}

// ---------------------------------------------------------------------------
// Pass 1, R25: apply the R19/R21 "shrink per-wave state" lever.  R21's
// pass1 held Kf[8][2]=64 + Dacc 32 + 2-deep prefetch 32 ~ 140 live regs ->
// (256,3) = 3 waves/SIMD.  k-window 128->64 (Kf 32, Dacc 16) + 1-deep
// prefetch (16) ~ 80 live -> (256,4) = 4 waves/SIMD, 48-reg spill margin.
// qc=2 (512 q/wave, 32 steps, R13-proven per-wave shape).  Grid 16 groups
// x 64 k-subs = 1024 blocks = 4 blocks/CU.  D2 back to 2 partials.
// ---------------------------------------------------------------------------
__global__ __launch_bounds__(256, 4) void k_pass1(const u16* __restrict__ Q,
                                                  const u16* __restrict__ Km,
                                                  float* __restrict__ D2)
{
    __shared__ float Dred[64];
    int g, sub;
    xcd_decode64(blockIdx.x, g, sub);
    int nh = g & 7, qc = g >> 3, k0 = sub * 64;
    const u16* Qh = Q + (long)nh * SEQ * 64;
    const u16* Kh = Km + (long)nh * SEQ * 64;
    int t = threadIdx.x, w = t >> 6, lane = t & 63, quad = lane >> 4, l16 = lane & 15;
    bf16x8 Kf[4][2];
    #pragma unroll
    for (int i = 0; i < 4; i++) {
        Kf[i][0] = *(const bf16x8*)&Kh[(k0 + i * 16 + l16) * 64 + quad * 8];
        Kf[i][1] = *(const bf16x8*)&Kh[(k0 + i * 16 + l16) * 64 + 32 + quad * 8];
    }
    if (t < 64) Dred[t] = 0.f;
    f32x4 z = {0.f, 0.f, 0.f, 0.f};
    float Dacc[4][4] = {};
    const int qw0 = qc * 2048 + w * 512;
    bf16x8 b0 = *(const bf16x8*)&Qh[(qw0 + l16) * 64 + quad * 8];
    bf16x8 b1 = *(const bf16x8*)&Qh[(qw0 + l16) * 64 + 32 + quad * 8];
    for (int step = 0; step < 32; step++) {
        int q = qw0 + step * 16;
        bf16x8 n0, n1;
        if (step < 31) {
            n0 = *(const bf16x8*)&Qh[(q + 16 + l16) * 64 + quad * 8];
            n1 = *(const bf16x8*)&Qh[(q + 16 + l16) * 64 + 32 + quad * 8];
        }
        #pragma unroll
        for (int i = 0; i < 4; i++) {
            f32x4 acc = z;
            acc = __builtin_amdgcn_mfma_f32_16x16x32_bf16(Kf[i][0], b0, acc, 0, 0, 0);
            acc = __builtin_amdgcn_mfma_f32_16x16x32_bf16(Kf[i][1], b1, acc, 0, 0, 0);
            #pragma unroll
            for (int r = 0; r < 4; r++) Dacc[i][r] += fexp2(acc[r]);
        }
        b0 = n0; b1 = n1;
    }
    #pragma unroll
    for (int i = 0; i < 4; i++)
        #pragma unroll
        for (int r = 0; r < 4; r++) {
            float v = Dacc[i][r];
            v += __shfl_xor(v, 1); v += __shfl_xor(v, 2);
            v += __shfl_xor(v, 4); v += __shfl_xor(v, 8);
            Dacc[i][r] = v;
        }
    __syncthreads();
    if (l16 == 0) {
        #pragma unroll
        for (int i = 0; i < 4; i++)
            #pragma unroll
            for (int r = 0; r < 4; r++)
                atomicAdd(&Dred[i * 16 + quad * 4 + r], Dacc[i][r]);
    }
    __syncthreads();
    if (t < 64) D2[((long)(qc * NHT + nh)) * SEQ + k0 + t] = Dred[t];
}

// ---------------------------------------------------------------------------
// V pre-scale (R16-proven): z[q,k] = exp(S)/D[k], so fold 1/D into V once.
// D2 has 2 qc-partials (R21 config).
// ---------------------------------------------------------------------------
__global__ __launch_bounds__(256) void k_vdiv(const float* __restrict__ Vf,
                                              const float* __restrict__ D2,
                                              u16* __restrict__ Vto)
{
    int b = blockIdx.x;
    int nh = b >> 6, d = b & 63;
    const float* Da = D2 + (long)nh * SEQ;
    const float* Db = Da + (long)NHT * SEQ;
    const float* src = Vf + ((long)nh * 64 + d) * SEQ;
    u16* dst = Vto + ((long)nh * 64 + d) * SEQ;
    int t = threadIdx.x;
    #pragma unroll
    for (int half = 0; half < 2; half++) {
        int k = half * 2048 + t * 8;
        float4 va = *(const float4*)&src[k];
        float4 vb = *(const float4*)&src[k + 4];
        float4 a0 = *(const float4*)&Da[k], a1 = *(const float4*)&Da[k + 4];
        float4 b0 = *(const float4*)&Db[k], b1 = *(const float4*)&Db[k + 4];
        float o[8];
        o[0] = va.x / (a0.x + b0.x); o[1] = va.y / (a0.y + b0.y);
        o[2] = va.z / (a0.z + b0.z); o[3] = va.w / (a0.w + b0.w);
        o[4] = vb.x / (a1.x + b1.x); o[5] = vb.y / (a1.y + b1.y);
        o[6] = vb.z / (a1.z + b1.z); o[7] = vb.w / (a1.w + b1.w);
        uint4 pk;
        pk.x = (u32)f2bf(o[0]) | ((u32)f2bf(o[1]) << 16);
        pk.y = (u32)f2bf(o[2]) | ((u32)f2bf(o[3]) << 16);
        pk.z = (u32)f2bf(o[4]) | ((u32)f2bf(o[5]) << 16);
        pk.w = (u32)f2bf(o[6]) | ((u32)f2bf(o[7]) << 16);
        *(uint4*)&dst[k] = pk;
    }
}

// ---------------------------------------------------------------------------
// Pass 2: exact R21 config (proven 49.7 µs, MfmaUtil 26.6, VGPR 76, no
// spill) — FROZEN.  d-split waves, 64-k stripes, kcid=2 (2048-k window, 32
// stripes), grid 512, (256,3).  R24's kcid=4 A/B proved more occupancy
// does NOT help this structure (55.2 µs at 22.4%): halved Qf amortization
// + doubled partial traffic eat the gain.  kcid=2 is the local optimum.
// ---------------------------------------------------------------------------
__global__ __launch_bounds__(256, 3) void k_pass2(const u16* __restrict__ Q,
                                                  const u16* __restrict__ Km,
                                                  const u16* __restrict__ Vt,
                                                  float* __restrict__ acat2)
{
    __shared__ __align__(16) u16 lP2[2][128][68];   // 34816 B
    float (*red)[68] = (float(*)[68])lP2;           // 34816 B overlay (epilogue)

    int g, sub;
    xcd_decode(blockIdx.x, g, sub);
    int nh = g & 7, kcid = g >> 3, q0 = sub * 128;
    int n = nh >> 2, h = nh & 3;
    const u16* Qh = Q + (long)nh * SEQ * 64;
    const u16* Kh = Km + (long)nh * SEQ * 64;
    const u16* Vh = Vt + (long)nh * 64 * SEQ;
    int t = threadIdx.x, w = t >> 6, lane = t & 63, quad = lane >> 4, l16 = lane & 15;
    const int kblk = kcid * 2048;
    const int dw = w * 16 + l16;     // this wave's V/output d rows

    // Q frags for the full 128-q tile
    bf16x8 Qf[8][2];
    #pragma unroll
    for (int jq = 0; jq < 8; jq++)
        #pragma unroll
        for (int ch = 0; ch < 2; ch++)
            Qf[jq][ch] = *(const bf16x8*)&Qh[(q0 + jq * 16 + l16) * 64 + ch * 32 + quad * 8];

    f32x4 z = {0.f, 0.f, 0.f, 0.f};
    f32x4 acc[8];
    #pragma unroll
    for (int jq = 0; jq < 8; jq++) acc[jq] = z;

// K for stripe I, this wave's 16 k-rows (slab w)
#define LOAD_K(KA, I)                                                         \
    {                                                                         \
        int _kb = kblk + (I) * 64 + w * 16;                                   \
        KA[0] = *(const bf16x8*)&Kh[(_kb + l16) * 64 + quad * 8];             \
        KA[1] = *(const bf16x8*)&Kh[(_kb + l16) * 64 + 32 + quad * 8];        \
    }
// V for stripe I, this wave's 16-d quarter, 2 k-halves of the 64-k stripe
#define LOAD_V(VB, I)                                                         \
    {                                                                         \
        int _kb = kblk + (I) * 64;                                            \
        VB[0] = *(const bf16x8*)&Vh[(long)dw * SEQ + _kb + quad * 8];         \
        VB[1] = *(const bf16x8*)&Vh[(long)dw * SEQ + _kb + 32 + quad * 8];    \
    }
// QK for this wave's 16-k slab -> lP2[B], columns w*16..w*16+15
#define QK_STRIPE(KA, B)                                                      \
    {                                                                         \
        _Pragma("unroll")                                                     \
        for (int jq = 0; jq < 8; jq++) {                                      \
            f32x4 s_ = z;                                                     \
            s_ = __builtin_amdgcn_mfma_f32_16x16x32_bf16(KA[0], Qf[jq][0], s_, 0, 0, 0); \
            s_ = __builtin_amdgcn_mfma_f32_16x16x32_bf16(KA[1], Qf[jq][1], s_, 0, 0, 0); \
            u32 e0 = __float_as_uint(fexp2(s_[0]));                           \
            u32 e1 = __float_as_uint(fexp2(s_[1]));                           \
            u32 e2 = __float_as_uint(fexp2(s_[2]));                           \
            u32 e3 = __float_as_uint(fexp2(s_[3]));                           \
            uint2 pk;                                                         \
            pk.x = __builtin_amdgcn_perm(e1, e0, 0x07060302u);                \
            pk.y = __builtin_amdgcn_perm(e3, e2, 0x07060302u);                \
            *(uint2*)&lP2[B][jq * 16 + l16][w * 16 + quad * 4] = pk;          \
        }                                                                     \
    }
// PV: this wave's 16-d quarter over the full 64-k stripe in buffer B
#define PV_STRIPE(VB, B)                                                      \
    {                                                                         \
        _Pragma("unroll")                                                     \
        for (int ks = 0; ks < 2; ks++) {                                      \
            _Pragma("unroll")                                                 \
            for (int jq = 0; jq < 8; jq++) {                                  \
                bf16x8 pa = *(const bf16x8*)&lP2[B][jq * 16 + l16][ks * 32 + quad * 8]; \
                acc[jq] = __builtin_amdgcn_mfma_f32_16x16x32_bf16(pa, VB[ks], acc[jq], 0, 0, 0); \
            }                                                                 \
        }                                                                     \
    }

    bf16x8 kA0[2], kA1[2], vb0[2], vb1[2];
    LOAD_K(kA0, 0)
    LOAD_V(vb0, 0)
    LOAD_K(kA1, 1)
    LOAD_V(vb1, 1)

    QK_STRIPE(kA0, 0)
    __syncthreads();
    for (int it = 0; it < 15; it++) {
        int i = it * 2;
        // stripe i (buf0) PV; QK(i+1)->buf1 first
        QK_STRIPE(kA1, 1)
        LOAD_K(kA0, i + 2)
        PV_STRIPE(vb0, 0)
        LOAD_V(vb0, i + 2)
        __syncthreads();
        // stripe i+1 (buf1) PV; QK(i+2)->buf0
        QK_STRIPE(kA0, 0)
        LOAD_K(kA1, i + 3)
        PV_STRIPE(vb1, 1)
        LOAD_V(vb1, i + 3)
        __syncthreads();
    }
    // stripe 31 QK -> buf1; stripe 30 PV <- buf0
    QK_STRIPE(kA1, 1)
    PV_STRIPE(vb0, 0)
    __syncthreads();
    // stripe 31 PV <- buf1
    PV_STRIPE(vb1, 1)

#undef LOAD_K
#undef LOAD_V
#undef QK_STRIPE
#undef PV_STRIPE

    // red overlays BOTH P buffers -> barrier before overwrite
    __syncthreads();
    #pragma unroll
    for (int jq = 0; jq < 8; jq++)
        #pragma unroll
        for (int r = 0; r < 4; r++)
            red[jq * 16 + quad * 4 + r][dw] = acc[jq][r];
    __syncthreads();
    float* dst = acat2 + (long)kcid * 8192 * 256;
    #pragma unroll
    for (int p = 0; p < 8; p++) {
        int row = p * 16 + (t >> 4);
        int ch = (t & 15) * 4;
        float4 o = *(float4*)&red[row][ch];
        *(float4*)&dst[((long)n * SEQ + q0 + row) * 256 + h * 64 + ch] = o;
    }
}

// ---------------------------------------------------------------------------
// Fused tail: LN2 + MLP + residual + transposed store (R12-proven).
// Sums 2 acat2 partials (R21 config).
// ---------------------------------------------------------------------------
__global__ __launch_bounds__(256) void k_tail(const float* __restrict__ x,
                                              const float* __restrict__ acat2,
                                              const float* __restrict__ lnw,
                                              const float* __restrict__ lnb,
                                              const u16* __restrict__ W1t,
                                              const float* __restrict__ b1v,
                                              const u16* __restrict__ W2t,
                                              const float* __restrict__ b2v,
                                              float* __restrict__ out)
{
    __shared__ __align__(16) unsigned char smem[16448];  // tile fp32 / lT u16
    float (*tile)[257] = (float(*)[257])smem;            // [16][257]
    u16 (*lT)[264] = (u16(*)[264])smem;                  // [16][264] overlay
    __shared__ float aF[16][257];                        // folded acat cache
    __shared__ float mu[16], rs[16];
    __shared__ __align__(16) u16 lH[16][264];

    const long STRIDE = (long)8192 * 256;
    int m0 = blockIdx.x * 16;
    int n = m0 >> 12, s0 = m0 & 4095;
    int t = threadIdx.x, w = t >> 6, lane = t & 63, quad = lane >> 4, l16 = lane & 15;

    {
        int sl = t & 15, cg = t >> 4;
        for (int cc = 0; cc < 256; cc += 16) {
            int c = cc + cg;
            tile[sl][c] = x[(n * 256 + c) * SEQ + s0 + sl];
        }
    }
    __syncthreads();
    for (int s = 0; s < 16; s++) {
        long idx = (long)(m0 + s) * 256 + t;
        float a = acat2[idx] + acat2[idx + STRIDE];
        aF[s][t] = a;
        tile[s][t] += a;
    }
    __syncthreads();
    {
        int l = t & 63;
        for (int rr = 0; rr < 4; rr++) {
            int s = w * 4 + rr;
            float a0 = tile[s][l], a1 = tile[s][l + 64], a2 = tile[s][l + 128], a3 = tile[s][l + 192];
            float sm = a0 + a1 + a2 + a3;
            float sq = a0 * a0 + a1 * a1 + a2 * a2 + a3 * a3;
            for (int off = 32; off; off >>= 1) { sm += __shfl_xor(sm, off); sq += __shfl_xor(sq, off); }
            if (l == 0) {
                float m = sm * (1.f / 256.f);
                mu[s] = m;
                rs[s] = rsqrtf(sq * (1.f / 256.f) - m * m + 1e-5f);
            }
        }
    }
    __syncthreads();
    {
        float ww = lnw[t], bb = lnb[t];
        for (int s = 0; s < 16; s++)
            lH[s][t] = f2bf((tile[s][t] - mu[s]) * rs[s] * ww + bb);
    }
    __syncthreads();

    f32x4 z = {0.f, 0.f, 0.f, 0.f};
    f32x4 acc1[4];
    #pragma unroll
    for (int js = 0; js < 4; js++) acc1[js] = z;
    #pragma unroll
    for (int kc = 0; kc < 8; kc++) {
        bf16x8 b = *(const bf16x8*)&lH[l16][kc * 32 + quad * 8];
        #pragma unroll
        for (int js = 0; js < 4; js++) {
            bf16x8 a = *(const bf16x8*)&W1t[(long)(w * 64 + js * 16 + l16) * 256 + kc * 32 + quad * 8];
            acc1[js] = __builtin_amdgcn_mfma_f32_16x16x32_bf16(a, b, acc1[js], 0, 0, 0);
        }
    }
    #pragma unroll
    for (int js = 0; js < 4; js++) {
        u32 e[4];
        #pragma unroll
        for (int r = 0; r < 4; r++) {
            int j = w * 64 + js * 16 + quad * 4 + r;
            float v = acc1[js][r] + b1v[j];
            float g = 0.5f * v * (1.f + erff(v * 0.70710678118f));
            u32 u = __float_as_uint(g);
            e[r] = u + 0x7fffu + ((u >> 16) & 1u);
        }
        uint2 pk;
        pk.x = __builtin_amdgcn_perm(e[1], e[0], 0x07060302u);
        pk.y = __builtin_amdgcn_perm(e[3], e[2], 0x07060302u);
        *(uint2*)&lT[l16][w * 64 + js * 16 + quad * 4] = pk;
    }
    __syncthreads();
    f32x4 acc2[4];
    #pragma unroll
    for (int cs = 0; cs < 4; cs++) acc2[cs] = z;
    #pragma unroll
    for (int kc = 0; kc < 8; kc++) {
        bf16x8 pa = *(const bf16x8*)&lT[l16][kc * 32 + quad * 8];
        #pragma unroll
        for (int cs = 0; cs < 4; cs++) {
            bf16x8 wb = *(const bf16x8*)&W2t[(long)(w * 64 + cs * 16 + l16) * 256 + kc * 32 + quad * 8];
            acc2[cs] = __builtin_amdgcn_mfma_f32_16x16x32_bf16(pa, wb, acc2[cs], 0, 0, 0);
        }
    }
    #pragma unroll
    for (int cs = 0; cs < 4; cs++) {
        int c = w * 64 + cs * 16 + l16;
        float bj = b2v[c];
        float vv[4];
        #pragma unroll
        for (int r = 0; r < 4; r++)
            vv[r] = acc2[cs][r] + bj + aF[quad * 4 + r][c];
        float4 o = make_float4(vv[0], vv[1], vv[2], vv[3]);
        *(float4*)&out[((long)n * 256 + c) * SEQ + s0 + quad * 4] = o;
    }
}

// ---------------------------------------------------------------------------
extern "C" void kernel_launch(void* const* d_in, const int* in_sizes, int n_in,
                              void* d_out, int out_size, void* d_ws, size_t ws_size,
                              hipStream_t stream) {
    const float* x    = (const float*)d_in[0];
    const float* ln1w = (const float*)d_in[1];
    const float* ln1b = (const float*)d_in[2];
    const float* WQ   = (const float*)d_in[3];
    const float* WK   = (const float*)d_in[4];
    const float* WV   = (const float*)d_in[5];
    const float* ln2w = (const float*)d_in[6];
    const float* ln2b = (const float*)d_in[7];
    const float* W1   = (const float*)d_in[8];
    const float* b1   = (const float*)d_in[9];
    const float* W2   = (const float*)d_in[10];
    const float* b2   = (const float*)d_in[11];
    float* out = (float*)d_out;

    char* p = (char*)d_ws;
    u16* norm   = (u16*)p;   p += (size_t)8192 * 256 * 2;
    u16* BtQKV  = (u16*)p;   p += (size_t)768 * 256 * 2;
    u16* W1t    = (u16*)p;   p += (size_t)256 * 256 * 2;
    u16* W2t    = (u16*)p;   p += (size_t)256 * 256 * 2;
    u16* Qb     = (u16*)p;   p += (size_t)NHT * SEQ * 64 * 2;
    u16* Kb     = (u16*)p;   p += (size_t)NHT * SEQ * 64 * 2;
    u16* VtT    = (u16*)p;   p += (size_t)NHT * SEQ * 64 * 2;
    float* D2   = (float*)p; p += (size_t)2 * NHT * SEQ * 4;
    float* acat2= (float*)p; p += (size_t)2 * 8192 * 256 * 4;
    // Vf (f32 transposed V, 8.4 MB) overlays acat2: qkv writes it, vdiv
    // consumes it, THEN pass2 overwrites acat2 — stream-ordered, no extra ws.
    float* Vf   = acat2;

    k_prep<<<1536, 256, 0, stream>>>(x, ln1w, ln1b, WQ, WK, WV, W1, W2,
                                     norm, BtQKV, W1t, W2t);
    k_qkv<<<dim3(128, 6), 256, 0, stream>>>(norm, BtQKV, Qb, Kb, Vf);
    k_pass1<<<1024, 256, 0, stream>>>(Qb, Kb, D2);
    k_vdiv<<<512, 256, 0, stream>>>(Vf, D2, VtT);
    k_pass2<<<512, 256, 0, stream>>>(Qb, Kb, VtT, acat2);
    k_tail<<<512, 256, 0, stream>>>(x, acat2, ln2w, ln2b, W1t, b1, W2t, b2, out);
}

// Round 14
// 223.872 us; speedup vs baseline: 1.3553x; 1.0183x over previous
//
#include <hip/hip_runtime.h>
#include <math.h>

#define SEQ 4096
#define CH  256
#define NHT 8      // N * HEADS
#define DHD 64

// Q is pre-scaled by log2(e)/64 at projection time, so both attention passes
// compute exp2(S) with zero multiplies.
#define QSCALE 0.0225421092f

using bf16x8 = __attribute__((ext_vector_type(8))) short;
using f32x4  = __attribute__((ext_vector_type(4))) float;
typedef unsigned short u16;
typedef unsigned int   u32;

__device__ __forceinline__ u16 f2bf(float f) {
    u32 u = __float_as_uint(f);
    u = (u + 0x7fffu + ((u >> 16) & 1u)) >> 16;
    return (u16)u;
}
__device__ __forceinline__ float bf2f(u16 h) {
    return __uint_as_float(((u32)h) << 16);
}
// raw v_exp_f32 — exp2f without -ffast-math is an OCML call (~8 VALU ops)
__device__ __forceinline__ float fexp2(float x) {
    return __builtin_amdgcn_exp2f(x);
}

// ---------------------------------------------------------------------------
// Prep: weight pack (blocks 0..1279) + LN1 (blocks 1280..1535), one launch.
// ---------------------------------------------------------------------------
__global__ __launch_bounds__(256) void k_prep(const float* __restrict__ x,
                                              const float* __restrict__ ln1w,
                                              const float* __restrict__ ln1b,
                                              const float* __restrict__ WQ,
                                              const float* __restrict__ WK,
                                              const float* __restrict__ WV,
                                              const float* __restrict__ W1,
                                              const float* __restrict__ W2,
                                              u16* __restrict__ norm,
                                              u16* __restrict__ BtQKV,
                                              u16* __restrict__ W1t,
                                              u16* __restrict__ W2t)
{
    __shared__ float tile[32][257];
    __shared__ float mu[32], rs[32];
    int bid = blockIdx.x;
    int t = threadIdx.x;
    if (bid < 1280) {   // ---- pack ----
        int id = bid * 256 + t;
        if (id < 768 * 256) {
            int j = id >> 8, c = id & 255;
            int which = j >> 8, h = (j >> 6) & 3, d = j & 63;
            const float* W = (which == 0) ? WQ : (which == 1) ? WK : WV;
            BtQKV[id] = f2bf(W[(h * 256 + c) * 64 + d]);
        } else if (id < 768 * 256 + 65536) {
            int jj = id - 768 * 256;
            int j = jj >> 8, c = jj & 255;
            W1t[jj] = f2bf(W1[c * 256 + j]);
        } else if (id < 768 * 256 + 2 * 65536) {
            int jj = id - 768 * 256 - 65536;
            int j = jj >> 8, c = jj & 255;
            W2t[jj] = f2bf(W2[c * 256 + j]);
        }
        return;
    }
    // ---- LN1 ----
    int b2i = bid - 1280;
    int n = b2i >> 7, s0 = (b2i & 127) * 32;
    int sl = t & 31, cg = t >> 5;
    for (int cc = 0; cc < 256; cc += 8) {
        int c = cc + cg;
        tile[sl][c] = x[(n * 256 + c) * SEQ + s0 + sl];
    }
    __syncthreads();
    int wv = t >> 6, l = t & 63;
    for (int rr = 0; rr < 8; rr++) {
        int s = wv * 8 + rr;
        float a0 = tile[s][l], a1 = tile[s][l + 64], a2 = tile[s][l + 128], a3 = tile[s][l + 192];
        float sm = a0 + a1 + a2 + a3;
        float sq = a0 * a0 + a1 * a1 + a2 * a2 + a3 * a3;
        for (int off = 32; off; off >>= 1) { sm += __shfl_xor(sm, off); sq += __shfl_xor(sq, off); }
        if (l == 0) {
            float m = sm * (1.f / 256.f);
            mu[s] = m;
            rs[s] = rsqrtf(sq * (1.f / 256.f) - m * m + 1e-5f);
        }
    }
    __syncthreads();
    float ww = ln1w[t], bb = ln1b[t];
    for (int s = 0; s < 32; s++) {
        float v = (tile[s][t] - mu[s]) * rs[s] * ww + bb;
        norm[(n * SEQ + s0 + s) * 256 + t] = f2bf(v);
    }
}

// ---------------------------------------------------------------------------
// QKV projection, barrier-free (R4-proven). Q pre-scaled by QSCALE.
// V written transposed in FP32 (Vf[nh][d][k]); k_vdiv rounds to bf16 once.
// ---------------------------------------------------------------------------
__global__ __launch_bounds__(256) void k_qkv(const u16* __restrict__ norm,
                                             const u16* __restrict__ Bt,
                                             u16* __restrict__ Qo,
                                             u16* __restrict__ Ko,
                                             float* __restrict__ Vfo)
{
    int m0 = blockIdx.x * 64, j0 = blockIdx.y * 128;
    int t = threadIdx.x, w = t >> 6, lane = t & 63, quad = lane >> 4, l16 = lane & 15;
    const u16* Ap = norm + (long)(m0 + w * 16 + l16) * 256;
    const u16* Bp = Bt + (long)j0 * 256;
    f32x4 z = {0.f, 0.f, 0.f, 0.f};
    f32x4 acc[8];
    #pragma unroll
    for (int j = 0; j < 8; j++) acc[j] = z;
    #pragma unroll
    for (int kc = 0; kc < 8; kc++) {
        bf16x8 a = *(const bf16x8*)&Ap[kc * 32 + quad * 8];
        #pragma unroll
        for (int j = 0; j < 8; j++) {
            bf16x8 b = *(const bf16x8*)&Bp[(long)(j * 16 + l16) * 256 + kc * 32 + quad * 8];
            acc[j] = __builtin_amdgcn_mfma_f32_16x16x32_bf16(a, b, acc[j], 0, 0, 0);
        }
    }
    #pragma unroll
    for (int j = 0; j < 8; j++) {
        int col = j0 + j * 16 + l16;
        int which = col >> 8, h = (col >> 6) & 3, d = col & 63;
        int m = m0 + w * 16 + quad * 4;
        int n = m >> 12, s = m & 4095;
        if (which == 2) {
            float4 o = make_float4(acc[j][0], acc[j][1], acc[j][2], acc[j][3]);
            *(float4*)&Vfo[((long)(n * 4 + h) * 64 + d) * SEQ + s] = o;
        } else {
            u16* dst = (which == 0) ? Qo : Ko;
            float sc = (which == 0) ? QSCALE : 1.0f;
            #pragma unroll
            for (int r = 0; r < 4; r++)
                dst[((n * 4 + h) * SEQ + s + r) * 64 + d] = f2bf(acc[j][r] * sc);
        }
    }
}

// ---------------------------------------------------------------------------
// XCD-group swizzles (R16-proven: FETCH 37.5->8.3 MB).
// pass2 (512 blocks): 16 groups x 32 subs; group g on XCD g>>1.
// pass1 (1024 blocks): 32 groups (nh x qc) x 32 subs; group g on XCD g>>2.
// ---------------------------------------------------------------------------
__device__ __forceinline__ void xcd_decode(int s, int& g, int& sub) {
    int xcd = s & 7, m = s >> 3;
    g = xcd * 2 + (m >> 5);
    sub = m & 31;
}
__device__ __forceinline__ void xcd_decode32(int s, int& g, int& sub) {
    int xcd = s & 7, m = s >> 3;
    g = xcd * 4 + (m >> 5);
    sub = m & 31;
}

// ---------------------------------------------------------------------------
// Pass 1 (R21-proven config, restored): qc=4 grid 1024 + (256,3), k-window
// 128/block, 2-deep Q prefetch.  R25's k-64 variant DOUBLED Q-loads per
// MFMA (the R14 invariant violation) and regressed ~5 µs — reverted.
// ---------------------------------------------------------------------------
__global__ __launch_bounds__(256, 3) void k_pass1(const u16* __restrict__ Q,
                                                  const u16* __restrict__ Km,
                                                  float* __restrict__ D2)
{
    __shared__ float Dred[128];
    int g, sub;
    xcd_decode32(blockIdx.x, g, sub);
    int nh = g & 7, qc = g >> 3, k0 = sub * 128;
    const u16* Qh = Q + (long)nh * SEQ * 64;
    const u16* Kh = Km + (long)nh * SEQ * 64;
    int t = threadIdx.x, w = t >> 6, lane = t & 63, quad = lane >> 4, l16 = lane & 15;
    bf16x8 Kf[8][2];
    #pragma unroll
    for (int i = 0; i < 8; i++) {
        Kf[i][0] = *(const bf16x8*)&Kh[(k0 + i * 16 + l16) * 64 + quad * 8];
        Kf[i][1] = *(const bf16x8*)&Kh[(k0 + i * 16 + l16) * 64 + 32 + quad * 8];
    }
    if (t < 128) Dred[t] = 0.f;
    f32x4 z = {0.f, 0.f, 0.f, 0.f};
    float Dacc[8][4] = {};
    const int qw0 = qc * 1024 + w * 256;

#define P1_LOADQ(B0, B1, ST)                                                  \
    {                                                                         \
        int _q = qw0 + (ST) * 16 + l16;                                       \
        B0 = *(const bf16x8*)&Qh[_q * 64 + quad * 8];                         \
        B1 = *(const bf16x8*)&Qh[_q * 64 + 32 + quad * 8];                    \
    }
#define P1_STEP(B0, B1)                                                       \
    {                                                                         \
        _Pragma("unroll")                                                     \
        for (int i = 0; i < 8; i++) {                                         \
            f32x4 acc = z;                                                    \
            acc = __builtin_amdgcn_mfma_f32_16x16x32_bf16(Kf[i][0], B0, acc, 0, 0, 0); \
            acc = __builtin_amdgcn_mfma_f32_16x16x32_bf16(Kf[i][1], B1, acc, 0, 0, 0); \
            _Pragma("unroll")                                                 \
            for (int r = 0; r < 4; r++) Dacc[i][r] += fexp2(acc[r]);          \
        }                                                                     \
    }

    bf16x8 qa0, qa1, qb0, qb1;
    P1_LOADQ(qa0, qa1, 0)
    P1_LOADQ(qb0, qb1, 1)
    for (int st = 0; st < 16; st += 2) {
        P1_STEP(qa0, qa1)
        if (st + 2 < 16) { P1_LOADQ(qa0, qa1, st + 2) }
        P1_STEP(qb0, qb1)
        if (st + 3 < 16) { P1_LOADQ(qb0, qb1, st + 3) }
    }
#undef P1_LOADQ
#undef P1_STEP

    #pragma unroll
    for (int i = 0; i < 8; i++)
        #pragma unroll
        for (int r = 0; r < 4; r++) {
            float v = Dacc[i][r];
            v += __shfl_xor(v, 1); v += __shfl_xor(v, 2);
            v += __shfl_xor(v, 4); v += __shfl_xor(v, 8);
            Dacc[i][r] = v;
        }
    __syncthreads();
    if (l16 == 0) {
        #pragma unroll
        for (int i = 0; i < 8; i++)
            #pragma unroll
            for (int r = 0; r < 4; r++)
                atomicAdd(&Dred[i * 16 + quad * 4 + r], Dacc[i][r]);
    }
    __syncthreads();
    if (t < 128) D2[((long)(qc * NHT + nh)) * SEQ + k0 + t] = Dred[t];
}

// ---------------------------------------------------------------------------
// V pre-scale (R16-proven): z[q,k] = exp(S)/D[k], so fold 1/D into V once.
// D2 has 4 qc-partials (R21 config).
// ---------------------------------------------------------------------------
__global__ __launch_bounds__(256) void k_vdiv(const float* __restrict__ Vf,
                                              const float* __restrict__ D2,
                                              u16* __restrict__ Vto)
{
    int b = blockIdx.x;
    int nh = b >> 6, d = b & 63;
    const long QS = (long)NHT * SEQ;
    const float* Dp = D2 + (long)nh * SEQ;
    const float* src = Vf + ((long)nh * 64 + d) * SEQ;
    u16* dst = Vto + ((long)nh * 64 + d) * SEQ;
    int t = threadIdx.x;
    #pragma unroll
    for (int half = 0; half < 2; half++) {
        int k = half * 2048 + t * 8;
        float o[8];
        #pragma unroll
        for (int e = 0; e < 8; e++) {
            float dsum = Dp[k + e] + Dp[QS + k + e] + Dp[2 * QS + k + e] + Dp[3 * QS + k + e];
            o[e] = src[k + e] / dsum;
        }
        uint4 pk;
        pk.x = (u32)f2bf(o[0]) | ((u32)f2bf(o[1]) << 16);
        pk.y = (u32)f2bf(o[2]) | ((u32)f2bf(o[3]) << 16);
        pk.z = (u32)f2bf(o[4]) | ((u32)f2bf(o[5]) << 16);
        pk.w = (u32)f2bf(o[6]) | ((u32)f2bf(o[7]) << 16);
        *(uint4*)&dst[k] = pk;
    }
}

// ---------------------------------------------------------------------------
// Pass 2: exact R21 config (proven 49.7 µs, MfmaUtil 26.6, VGPR 76, no
// spill) — FROZEN.  d-split waves, 64-k stripes, kcid=2 (2048-k window, 32
// stripes), grid 512, (256,3).  R24's kcid=4 A/B proved more occupancy
// does NOT help (55.2 µs at 22.4%); the structure is LDS-read-bound.
// ---------------------------------------------------------------------------
__global__ __launch_bounds__(256, 3) void k_pass2(const u16* __restrict__ Q,
                                                  const u16* __restrict__ Km,
                                                  const u16* __restrict__ Vt,
                                                  float* __restrict__ acat2)
{
    __shared__ __align__(16) u16 lP2[2][128][68];   // 34816 B
    float (*red)[68] = (float(*)[68])lP2;           // 34816 B overlay (epilogue)

    int g, sub;
    xcd_decode(blockIdx.x, g, sub);
    int nh = g & 7, kcid = g >> 3, q0 = sub * 128;
    int n = nh >> 2, h = nh & 3;
    const u16* Qh = Q + (long)nh * SEQ * 64;
    const u16* Kh = Km + (long)nh * SEQ * 64;
    const u16* Vh = Vt + (long)nh * 64 * SEQ;
    int t = threadIdx.x, w = t >> 6, lane = t & 63, quad = lane >> 4, l16 = lane & 15;
    const int kblk = kcid * 2048;
    const int dw = w * 16 + l16;     // this wave's V/output d rows

    // Q frags for the full 128-q tile
    bf16x8 Qf[8][2];
    #pragma unroll
    for (int jq = 0; jq < 8; jq++)
        #pragma unroll
        for (int ch = 0; ch < 2; ch++)
            Qf[jq][ch] = *(const bf16x8*)&Qh[(q0 + jq * 16 + l16) * 64 + ch * 32 + quad * 8];

    f32x4 z = {0.f, 0.f, 0.f, 0.f};
    f32x4 acc[8];
    #pragma unroll
    for (int jq = 0; jq < 8; jq++) acc[jq] = z;

// K for stripe I, this wave's 16 k-rows (slab w)
#define LOAD_K(KA, I)                                                         \
    {                                                                         \
        int _kb = kblk + (I) * 64 + w * 16;                                   \
        KA[0] = *(const bf16x8*)&Kh[(_kb + l16) * 64 + quad * 8];             \
        KA[1] = *(const bf16x8*)&Kh[(_kb + l16) * 64 + 32 + quad * 8];        \
    }
// V for stripe I, this wave's 16-d quarter, 2 k-halves of the 64-k stripe
#define LOAD_V(VB, I)                                                         \
    {                                                                         \
        int _kb = kblk + (I) * 64;                                            \
        VB[0] = *(const bf16x8*)&Vh[(long)dw * SEQ + _kb + quad * 8];         \
        VB[1] = *(const bf16x8*)&Vh[(long)dw * SEQ + _kb + 32 + quad * 8];    \
    }
// QK for this wave's 16-k slab -> lP2[B], columns w*16..w*16+15
#define QK_STRIPE(KA, B)                                                      \
    {                                                                         \
        _Pragma("unroll")                                                     \
        for (int jq = 0; jq < 8; jq++) {                                      \
            f32x4 s_ = z;                                                     \
            s_ = __builtin_amdgcn_mfma_f32_16x16x32_bf16(KA[0], Qf[jq][0], s_, 0, 0, 0); \
            s_ = __builtin_amdgcn_mfma_f32_16x16x32_bf16(KA[1], Qf[jq][1], s_, 0, 0, 0); \
            u32 e0 = __float_as_uint(fexp2(s_[0]));                           \
            u32 e1 = __float_as_uint(fexp2(s_[1]));                           \
            u32 e2 = __float_as_uint(fexp2(s_[2]));                           \
            u32 e3 = __float_as_uint(fexp2(s_[3]));                           \
            uint2 pk;                                                         \
            pk.x = __builtin_amdgcn_perm(e1, e0, 0x07060302u);                \
            pk.y = __builtin_amdgcn_perm(e3, e2, 0x07060302u);                \
            *(uint2*)&lP2[B][jq * 16 + l16][w * 16 + quad * 4] = pk;          \
        }                                                                     \
    }
// PV: this wave's 16-d quarter over the full 64-k stripe in buffer B
#define PV_STRIPE(VB, B)                                                      \
    {                                                                         \
        _Pragma("unroll")                                                     \
        for (int ks = 0; ks < 2; ks++) {                                      \
            _Pragma("unroll")                                                 \
            for (int jq = 0; jq < 8; jq++) {                                  \
                bf16x8 pa = *(const bf16x8*)&lP2[B][jq * 16 + l16][ks * 32 + quad * 8]; \
                acc[jq] = __builtin_amdgcn_mfma_f32_16x16x32_bf16(pa, VB[ks], acc[jq], 0, 0, 0); \
            }                                                                 \
        }                                                                     \
    }

    bf16x8 kA0[2], kA1[2], vb0[2], vb1[2];
    LOAD_K(kA0, 0)
    LOAD_V(vb0, 0)
    LOAD_K(kA1, 1)
    LOAD_V(vb1, 1)

    QK_STRIPE(kA0, 0)
    __syncthreads();
    for (int it = 0; it < 15; it++) {
        int i = it * 2;
        // stripe i (buf0) PV; QK(i+1)->buf1 first
        QK_STRIPE(kA1, 1)
        LOAD_K(kA0, i + 2)
        PV_STRIPE(vb0, 0)
        LOAD_V(vb0, i + 2)
        __syncthreads();
        // stripe i+1 (buf1) PV; QK(i+2)->buf0
        QK_STRIPE(kA0, 0)
        LOAD_K(kA1, i + 3)
        PV_STRIPE(vb1, 1)
        LOAD_V(vb1, i + 3)
        __syncthreads();
    }
    // stripe 31 QK -> buf1; stripe 30 PV <- buf0
    QK_STRIPE(kA1, 1)
    PV_STRIPE(vb0, 0)
    __syncthreads();
    // stripe 31 PV <- buf1
    PV_STRIPE(vb1, 1)

#undef LOAD_K
#undef LOAD_V
#undef QK_STRIPE
#undef PV_STRIPE

    // red overlays BOTH P buffers -> barrier before overwrite
    __syncthreads();
    #pragma unroll
    for (int jq = 0; jq < 8; jq++)
        #pragma unroll
        for (int r = 0; r < 4; r++)
            red[jq * 16 + quad * 4 + r][dw] = acc[jq][r];
    __syncthreads();
    float* dst = acat2 + (long)kcid * 8192 * 256;
    #pragma unroll
    for (int p = 0; p < 8; p++) {
        int row = p * 16 + (t >> 4);
        int ch = (t & 15) * 4;
        float4 o = *(float4*)&red[row][ch];
        *(float4*)&dst[((long)n * SEQ + q0 + row) * 256 + h * 64 + ch] = o;
    }
}

// ---------------------------------------------------------------------------
// Fused tail: LN2 + MLP + residual + transposed store (R12-proven).
// Sums 2 acat2 partials (R21 config).
// ---------------------------------------------------------------------------
__global__ __launch_bounds__(256) void k_tail(const float* __restrict__ x,
                                              const float* __restrict__ acat2,
                                              const float* __restrict__ lnw,
                                              const float* __restrict__ lnb,
                                              const u16* __restrict__ W1t,
                                              const float* __restrict__ b1v,
                                              const u16* __restrict__ W2t,
                                              const float* __restrict__ b2v,
                                              float* __restrict__ out)
{
    __shared__ __align__(16) unsigned char smem[16448];  // tile fp32 / lT u16
    float (*tile)[257] = (float(*)[257])smem;            // [16][257]
    u16 (*lT)[264] = (u16(*)[264])smem;                  // [16][264] overlay
    __shared__ float aF[16][257];                        // folded acat cache
    __shared__ float mu[16], rs[16];
    __shared__ __align__(16) u16 lH[16][264];

    const long STRIDE = (long)8192 * 256;
    int m0 = blockIdx.x * 16;
    int n = m0 >> 12, s0 = m0 & 4095;
    int t = threadIdx.x, w = t >> 6, lane = t & 63, quad = lane >> 4, l16 = lane & 15;

    {
        int sl = t & 15, cg = t >> 4;
        for (int cc = 0; cc < 256; cc += 16) {
            int c = cc + cg;
            tile[sl][c] = x[(n * 256 + c) * SEQ + s0 + sl];
        }
    }
    __syncthreads();
    for (int s = 0; s < 16; s++) {
        long idx = (long)(m0 + s) * 256 + t;
        float a = acat2[idx] + acat2[idx + STRIDE];
        aF[s][t] = a;
        tile[s][t] += a;
    }
    __syncthreads();
    {
        int l = t & 63;
        for (int rr = 0; rr < 4; rr++) {
            int s = w * 4 + rr;
            float a0 = tile[s][l], a1 = tile[s][l + 64], a2 = tile[s][l + 128], a3 = tile[s][l + 192];
            float sm = a0 + a1 + a2 + a3;
            float sq = a0 * a0 + a1 * a1 + a2 * a2 + a3 * a3;
            for (int off = 32; off; off >>= 1) { sm += __shfl_xor(sm, off); sq += __shfl_xor(sq, off); }
            if (l == 0) {
                float m = sm * (1.f / 256.f);
                mu[s] = m;
                rs[s] = rsqrtf(sq * (1.f / 256.f) - m * m + 1e-5f);
            }
        }
    }
    __syncthreads();
    {
        float ww = lnw[t], bb = lnb[t];
        for (int s = 0; s < 16; s++)
            lH[s][t] = f2bf((tile[s][t] - mu[s]) * rs[s] * ww + bb);
    }
    __syncthreads();

    f32x4 z = {0.f, 0.f, 0.f, 0.f};
    f32x4 acc1[4];
    #pragma unroll
    for (int js = 0; js < 4; js++) acc1[js] = z;
    #pragma unroll
    for (int kc = 0; kc < 8; kc++) {
        bf16x8 b = *(const bf16x8*)&lH[l16][kc * 32 + quad * 8];
        #pragma unroll
        for (int js = 0; js < 4; js++) {
            bf16x8 a = *(const bf16x8*)&W1t[(long)(w * 64 + js * 16 + l16) * 256 + kc * 32 + quad * 8];
            acc1[js] = __builtin_amdgcn_mfma_f32_16x16x32_bf16(a, b, acc1[js], 0, 0, 0);
        }
    }
    #pragma unroll
    for (int js = 0; js < 4; js++) {
        u32 e[4];
        #pragma unroll
        for (int r = 0; r < 4; r++) {
            int j = w * 64 + js * 16 + quad * 4 + r;
            float v = acc1[js][r] + b1v[j];
            float g = 0.5f * v * (1.f + erff(v * 0.70710678118f));
            u32 u = __float_as_uint(g);
            e[r] = u + 0x7fffu + ((u >> 16) & 1u);
        }
        uint2 pk;
        pk.x = __builtin_amdgcn_perm(e[1], e[0], 0x07060302u);
        pk.y = __builtin_amdgcn_perm(e[3], e[2], 0x07060302u);
        *(uint2*)&lT[l16][w * 64 + js * 16 + quad * 4] = pk;
    }
    __syncthreads();
    f32x4 acc2[4];
    #pragma unroll
    for (int cs = 0; cs < 4; cs++) acc2[cs] = z;
    #pragma unroll
    for (int kc = 0; kc < 8; kc++) {
        bf16x8 pa = *(const bf16x8*)&lT[l16][kc * 32 + quad * 8];
        #pragma unroll
        for (int cs = 0; cs < 4; cs++) {
            bf16x8 wb = *(const bf16x8*)&W2t[(long)(w * 64 + cs * 16 + l16) * 256 + kc * 32 + quad * 8];
            acc2[cs] = __builtin_amdgcn_mfma_f32_16x16x32_bf16(pa, wb, acc2[cs], 0, 0, 0);
        }
    }
    #pragma unroll
    for (int cs = 0; cs < 4; cs++) {
        int c = w * 64 + cs * 16 + l16;
        float bj = b2v[c];
        float vv[4];
        #pragma unroll
        for (int r = 0; r < 4; r++)
            vv[r] = acc2[cs][r] + bj + aF[quad * 4 + r][c];
        float4 o = make_float4(vv[0], vv[1], vv[2], vv[3]);
        *(float4*)&out[((long)n * 256 + c) * SEQ + s0 + quad * 4] = o;
    }
}

// ---------------------------------------------------------------------------
extern "C" void kernel_launch(void* const* d_in, const int* in_sizes, int n_in,
                              void* d_out, int out_size, void* d_ws, size_t ws_size,
                              hipStream_t stream) {
    const float* x    = (const float*)d_in[0];
    const float* ln1w = (const float*)d_in[1];
    const float* ln1b = (const float*)d_in[2];
    const float* WQ   = (const float*)d_in[3];
    const float* WK   = (const float*)d_in[4];
    const float* WV   = (const float*)d_in[5];
    const float* ln2w = (const float*)d_in[6];
    const float* ln2b = (const float*)d_in[7];
    const float* W1   = (const float*)d_in[8];
    const float* b1   = (const float*)d_in[9];
    const float* W2   = (const float*)d_in[10];
    const float* b2   = (const float*)d_in[11];
    float* out = (float*)d_out;

    char* p = (char*)d_ws;
    u16* norm   = (u16*)p;   p += (size_t)8192 * 256 * 2;
    u16* BtQKV  = (u16*)p;   p += (size_t)768 * 256 * 2;
    u16* W1t    = (u16*)p;   p += (size_t)256 * 256 * 2;
    u16* W2t    = (u16*)p;   p += (size_t)256 * 256 * 2;
    u16* Qb     = (u16*)p;   p += (size_t)NHT * SEQ * 64 * 2;
    u16* Kb     = (u16*)p;   p += (size_t)NHT * SEQ * 64 * 2;
    u16* VtT    = (u16*)p;   p += (size_t)NHT * SEQ * 64 * 2;
    float* D2   = (float*)p; p += (size_t)4 * NHT * SEQ * 4;
    float* acat2= (float*)p; p += (size_t)2 * 8192 * 256 * 4;
    // Vf (f32 transposed V, 8.4 MB) overlays acat2: qkv writes it, vdiv
    // consumes it, THEN pass2 overwrites acat2 — stream-ordered, no extra ws.
    float* Vf   = acat2;

    k_prep<<<1536, 256, 0, stream>>>(x, ln1w, ln1b, WQ, WK, WV, W1, W2,
                                     norm, BtQKV, W1t, W2t);
    k_qkv<<<dim3(128, 6), 256, 0, stream>>>(norm, BtQKV, Qb, Kb, Vf);
    k_pass1<<<1024, 256, 0, stream>>>(Qb, Kb, D2);
    k_vdiv<<<512, 256, 0, stream>>>(Vf, D2, VtT);
    k_pass2<<<512, 256, 0, stream>>>(Qb, Kb, VtT, acat2);
    k_tail<<<512, 256, 0, stream>>>(x, acat2, ln2w, ln2b, W1t, b1, W2t, b2, out);
}

// Round 15
// 217.981 us; speedup vs baseline: 1.3919x; 1.0270x over previous
//
#include <hip/hip_runtime.h>
#include <math.h>

#define SEQ 4096
#define CH  256
#define NHT 8      // N * HEADS
#define DHD 64

// Q is pre-scaled by log2(e)/64 at projection time, so both attention passes
// compute exp2(S) with zero multiplies.
#define QSCALE 0.0225421092f

using bf16x8 = __attribute__((ext_vector_type(8))) short;
using f32x4  = __attribute__((ext_vector_type(4))) float;
typedef unsigned short u16;
typedef unsigned int   u32;

__device__ __forceinline__ u16 f2bf(float f) {
    u32 u = __float_as_uint(f);
    u = (u + 0x7fffu + ((u >> 16) & 1u)) >> 16;
    return (u16)u;
}
__device__ __forceinline__ float bf2f(u16 h) {
    return __uint_as_float(((u32)h) << 16);
}
// raw v_exp_f32 — exp2f without -ffast-math is an OCML call (~8 VALU ops)
__device__ __forceinline__ float fexp2(float x) {
    return __builtin_amdgcn_exp2f(x);
}

// ---------------------------------------------------------------------------
// Prep: weight pack (blocks 0..1279) + LN1 (blocks 1280..1535), one launch.
// ---------------------------------------------------------------------------
__global__ __launch_bounds__(256) void k_prep(const float* __restrict__ x,
                                              const float* __restrict__ ln1w,
                                              const float* __restrict__ ln1b,
                                              const float* __restrict__ WQ,
                                              const float* __restrict__ WK,
                                              const float* __restrict__ WV,
                                              const float* __restrict__ W1,
                                              const float* __restrict__ W2,
                                              u16* __restrict__ norm,
                                              u16* __restrict__ BtQKV,
                                              u16* __restrict__ W1t,
                                              u16* __restrict__ W2t)
{
    __shared__ float tile[32][257];
    __shared__ float mu[32], rs[32];
    int bid = blockIdx.x;
    int t = threadIdx.x;
    if (bid < 1280) {   // ---- pack ----
        int id = bid * 256 + t;
        if (id < 768 * 256) {
            int j = id >> 8, c = id & 255;
            int which = j >> 8, h = (j >> 6) & 3, d = j & 63;
            const float* W = (which == 0) ? WQ : (which == 1) ? WK : WV;
            BtQKV[id] = f2bf(W[(h * 256 + c) * 64 + d]);
        } else if (id < 768 * 256 + 65536) {
            int jj = id - 768 * 256;
            int j = jj >> 8, c = jj & 255;
            W1t[jj] = f2bf(W1[c * 256 + j]);
        } else if (id < 768 * 256 + 2 * 65536) {
            int jj = id - 768 * 256 - 65536;
            int j = jj >> 8, c = jj & 255;
            W2t[jj] = f2bf(W2[c * 256 + j]);
        }
        return;
    }
    // ---- LN1 ----
    int b2i = bid - 1280;
    int n = b2i >> 7, s0 = (b2i & 127) * 32;
    int sl = t & 31, cg = t >> 5;
    for (int cc = 0; cc < 256; cc += 8) {
        int c = cc + cg;
        tile[sl][c] = x[(n * 256 + c) * SEQ + s0 + sl];
    }
    __syncthreads();
    int wv = t >> 6, l = t & 63;
    for (int rr = 0; rr < 8; rr++) {
        int s = wv * 8 + rr;
        float a0 = tile[s][l], a1 = tile[s][l + 64], a2 = tile[s][l + 128], a3 = tile[s][l + 192];
        float sm = a0 + a1 + a2 + a3;
        float sq = a0 * a0 + a1 * a1 + a2 * a2 + a3 * a3;
        for (int off = 32; off; off >>= 1) { sm += __shfl_xor(sm, off); sq += __shfl_xor(sq, off); }
        if (l == 0) {
            float m = sm * (1.f / 256.f);
            mu[s] = m;
            rs[s] = rsqrtf(sq * (1.f / 256.f) - m * m + 1e-5f);
        }
    }
    __syncthreads();
    float ww = ln1w[t], bb = ln1b[t];
    for (int s = 0; s < 32; s++) {
        float v = (tile[s][t] - mu[s]) * rs[s] * ww + bb;
        norm[(n * SEQ + s0 + s) * 256 + t] = f2bf(v);
    }
}

// ---------------------------------------------------------------------------
// QKV projection, barrier-free (R4-proven). Q pre-scaled by QSCALE.
// V written transposed in FP32 (Vf[nh][d][k]); k_vdiv rounds to bf16 once.
// ---------------------------------------------------------------------------
__global__ __launch_bounds__(256) void k_qkv(const u16* __restrict__ norm,
                                             const u16* __restrict__ Bt,
                                             u16* __restrict__ Qo,
                                             u16* __restrict__ Ko,
                                             float* __restrict__ Vfo)
{
    int m0 = blockIdx.x * 64, j0 = blockIdx.y * 128;
    int t = threadIdx.x, w = t >> 6, lane = t & 63, quad = lane >> 4, l16 = lane & 15;
    const u16* Ap = norm + (long)(m0 + w * 16 + l16) * 256;
    const u16* Bp = Bt + (long)j0 * 256;
    f32x4 z = {0.f, 0.f, 0.f, 0.f};
    f32x4 acc[8];
    #pragma unroll
    for (int j = 0; j < 8; j++) acc[j] = z;
    #pragma unroll
    for (int kc = 0; kc < 8; kc++) {
        bf16x8 a = *(const bf16x8*)&Ap[kc * 32 + quad * 8];
        #pragma unroll
        for (int j = 0; j < 8; j++) {
            bf16x8 b = *(const bf16x8*)&Bp[(long)(j * 16 + l16) * 256 + kc * 32 + quad * 8];
            acc[j] = __builtin_amdgcn_mfma_f32_16x16x32_bf16(a, b, acc[j], 0, 0, 0);
        }
    }
    #pragma unroll
    for (int j = 0; j < 8; j++) {
        int col = j0 + j * 16 + l16;
        int which = col >> 8, h = (col >> 6) & 3, d = col & 63;
        int m = m0 + w * 16 + quad * 4;
        int n = m >> 12, s = m & 4095;
        if (which == 2) {
            float4 o = make_float4(acc[j][0], acc[j][1], acc[j][2], acc[j][3]);
            *(float4*)&Vfo[((long)(n * 4 + h) * 64 + d) * SEQ + s] = o;
        } else {
            u16* dst = (which == 0) ? Qo : Ko;
            float sc = (which == 0) ? QSCALE : 1.0f;
            #pragma unroll
            for (int r = 0; r < 4; r++)
                dst[((n * 4 + h) * SEQ + s + r) * 64 + d] = f2bf(acc[j][r] * sc);
        }
    }
}

// ---------------------------------------------------------------------------
// XCD-group swizzles (R16-proven: FETCH 37.5->8.3 MB).
// pass2 (512 blocks): 16 groups x 32 subs; group g on XCD g>>1.
// pass1 (1024 blocks): 32 groups (nh x qc) x 32 subs; group g on XCD g>>2.
// ---------------------------------------------------------------------------
__device__ __forceinline__ void xcd_decode(int s, int& g, int& sub) {
    int xcd = s & 7, m = s >> 3;
    g = xcd * 2 + (m >> 5);
    sub = m & 31;
}
__device__ __forceinline__ void xcd_decode32(int s, int& g, int& sub) {
    int xcd = s & 7, m = s >> 3;
    g = xcd * 4 + (m >> 5);
    sub = m & 31;
}

// ---------------------------------------------------------------------------
// Pass 1 (R21-proven config): qc=4 grid 1024 + (256,3), k-window 128/block,
// 2-deep Q prefetch.
// ---------------------------------------------------------------------------
__global__ __launch_bounds__(256, 3) void k_pass1(const u16* __restrict__ Q,
                                                  const u16* __restrict__ Km,
                                                  float* __restrict__ D2)
{
    __shared__ float Dred[128];
    int g, sub;
    xcd_decode32(blockIdx.x, g, sub);
    int nh = g & 7, qc = g >> 3, k0 = sub * 128;
    const u16* Qh = Q + (long)nh * SEQ * 64;
    const u16* Kh = Km + (long)nh * SEQ * 64;
    int t = threadIdx.x, w = t >> 6, lane = t & 63, quad = lane >> 4, l16 = lane & 15;
    bf16x8 Kf[8][2];
    #pragma unroll
    for (int i = 0; i < 8; i++) {
        Kf[i][0] = *(const bf16x8*)&Kh[(k0 + i * 16 + l16) * 64 + quad * 8];
        Kf[i][1] = *(const bf16x8*)&Kh[(k0 + i * 16 + l16) * 64 + 32 + quad * 8];
    }
    if (t < 128) Dred[t] = 0.f;
    f32x4 z = {0.f, 0.f, 0.f, 0.f};
    float Dacc[8][4] = {};
    const int qw0 = qc * 1024 + w * 256;

#define P1_LOADQ(B0, B1, ST)                                                  \
    {                                                                         \
        int _q = qw0 + (ST) * 16 + l16;                                       \
        B0 = *(const bf16x8*)&Qh[_q * 64 + quad * 8];                         \
        B1 = *(const bf16x8*)&Qh[_q * 64 + 32 + quad * 8];                    \
    }
#define P1_STEP(B0, B1)                                                       \
    {                                                                         \
        _Pragma("unroll")                                                     \
        for (int i = 0; i < 8; i++) {                                         \
            f32x4 acc = z;                                                    \
            acc = __builtin_amdgcn_mfma_f32_16x16x32_bf16(Kf[i][0], B0, acc, 0, 0, 0); \
            acc = __builtin_amdgcn_mfma_f32_16x16x32_bf16(Kf[i][1], B1, acc, 0, 0, 0); \
            _Pragma("unroll")                                                 \
            for (int r = 0; r < 4; r++) Dacc[i][r] += fexp2(acc[r]);          \
        }                                                                     \
    }

    bf16x8 qa0, qa1, qb0, qb1;
    P1_LOADQ(qa0, qa1, 0)
    P1_LOADQ(qb0, qb1, 1)
    for (int st = 0; st < 16; st += 2) {
        P1_STEP(qa0, qa1)
        if (st + 2 < 16) { P1_LOADQ(qa0, qa1, st + 2) }
        P1_STEP(qb0, qb1)
        if (st + 3 < 16) { P1_LOADQ(qb0, qb1, st + 3) }
    }
#undef P1_LOADQ
#undef P1_STEP

    #pragma unroll
    for (int i = 0; i < 8; i++)
        #pragma unroll
        for (int r = 0; r < 4; r++) {
            float v = Dacc[i][r];
            v += __shfl_xor(v, 1); v += __shfl_xor(v, 2);
            v += __shfl_xor(v, 4); v += __shfl_xor(v, 8);
            Dacc[i][r] = v;
        }
    __syncthreads();
    if (l16 == 0) {
        #pragma unroll
        for (int i = 0; i < 8; i++)
            #pragma unroll
            for (int r = 0; r < 4; r++)
                atomicAdd(&Dred[i * 16 + quad * 4 + r], Dacc[i][r]);
    }
    __syncthreads();
    if (t < 128) D2[((long)(qc * NHT + nh)) * SEQ + k0 + t] = Dred[t];
}

// ---------------------------------------------------------------------------
// V pre-scale (R16-proven): z[q,k] = exp(S)/D[k], so fold 1/D into V once.
// D2 has 4 qc-partials.
// ---------------------------------------------------------------------------
__global__ __launch_bounds__(256) void k_vdiv(const float* __restrict__ Vf,
                                              const float* __restrict__ D2,
                                              u16* __restrict__ Vto)
{
    int b = blockIdx.x;
    int nh = b >> 6, d = b & 63;
    const long QS = (long)NHT * SEQ;
    const float* Dp = D2 + (long)nh * SEQ;
    const float* src = Vf + ((long)nh * 64 + d) * SEQ;
    u16* dst = Vto + ((long)nh * 64 + d) * SEQ;
    int t = threadIdx.x;
    #pragma unroll
    for (int half = 0; half < 2; half++) {
        int k = half * 2048 + t * 8;
        float o[8];
        #pragma unroll
        for (int e = 0; e < 8; e++) {
            float dsum = Dp[k + e] + Dp[QS + k + e] + Dp[2 * QS + k + e] + Dp[3 * QS + k + e];
            o[e] = src[k + e] / dsum;
        }
        uint4 pk;
        pk.x = (u32)f2bf(o[0]) | ((u32)f2bf(o[1]) << 16);
        pk.y = (u32)f2bf(o[2]) | ((u32)f2bf(o[3]) << 16);
        pk.z = (u32)f2bf(o[4]) | ((u32)f2bf(o[5]) << 16);
        pk.w = (u32)f2bf(o[6]) | ((u32)f2bf(o[7]) << 16);
        *(uint4*)&dst[k] = pk;
    }
}

// ---------------------------------------------------------------------------
// Pass 2, R27: hybrid 2d x 2k wave split.  The d-split (R19/R21) makes all
// 4 waves read the ENTIRE P stripe (4x read amplification; LDS ~240 cyc vs
// MFMA ~155 per wave-stripe — the binding resource per R24's occupancy
// null).  Wave w = (dhalf=w>>1, khalf=w&1): owns 32 d-rows x its 32-k half
// of each stripe.  PV reads 8 b128/stripe instead of 16 (amplification
// 4x -> 2x); MFMA count, Q/K/V loads, and the QK phase are unchanged.
// acc 32->64 regs (~180 live); (256,2) is free (grid 512 = 2 blocks/CU is
// the residency today anyway) and its 256-reg cap rules out spill.
// Epilogue: 2-way cross-wave k-sum into red (khalf 0 writes, khalf 1 adds).
// ---------------------------------------------------------------------------
__global__ __launch_bounds__(256, 2) void k_pass2(const u16* __restrict__ Q,
                                                  const u16* __restrict__ Km,
                                                  const u16* __restrict__ Vt,
                                                  float* __restrict__ acat2)
{
    __shared__ __align__(16) u16 lP2[2][128][68];   // 34816 B
    float (*red)[68] = (float(*)[68])lP2;           // 34816 B overlay (epilogue)

    int g, sub;
    xcd_decode(blockIdx.x, g, sub);
    int nh = g & 7, kcid = g >> 3, q0 = sub * 128;
    int n = nh >> 2, h = nh & 3;
    const u16* Qh = Q + (long)nh * SEQ * 64;
    const u16* Kh = Km + (long)nh * SEQ * 64;
    const u16* Vh = Vt + (long)nh * 64 * SEQ;
    int t = threadIdx.x, w = t >> 6, lane = t & 63, quad = lane >> 4, l16 = lane & 15;
    const int kblk = kcid * 2048;
    const int dhalf = w >> 1, khalf = w & 1;

    // Q frags for the full 128-q tile
    bf16x8 Qf[8][2];
    #pragma unroll
    for (int jq = 0; jq < 8; jq++)
        #pragma unroll
        for (int ch = 0; ch < 2; ch++)
            Qf[jq][ch] = *(const bf16x8*)&Qh[(q0 + jq * 16 + l16) * 64 + ch * 32 + quad * 8];

    f32x4 z = {0.f, 0.f, 0.f, 0.f};
    f32x4 acc[8][2];
    #pragma unroll
    for (int jq = 0; jq < 8; jq++)
        #pragma unroll
        for (int jd = 0; jd < 2; jd++) acc[jq][jd] = z;

// K for stripe I, this wave's 16 k-rows (slab w, same as before)
#define LOAD_K(KA, I)                                                         \
    {                                                                         \
        int _kb = kblk + (I) * 64 + w * 16;                                   \
        KA[0] = *(const bf16x8*)&Kh[(_kb + l16) * 64 + quad * 8];             \
        KA[1] = *(const bf16x8*)&Kh[(_kb + l16) * 64 + 32 + quad * 8];        \
    }
// V for stripe I: this wave's 2 d-sixteens (dhalf), its 32-k half (khalf)
#define LOAD_V(VB, I)                                                         \
    {                                                                         \
        int _kb = kblk + (I) * 64 + khalf * 32;                               \
        VB[0] = *(const bf16x8*)&Vh[(long)(dhalf * 32 + l16) * SEQ + _kb + quad * 8];      \
        VB[1] = *(const bf16x8*)&Vh[(long)(dhalf * 32 + 16 + l16) * SEQ + _kb + quad * 8]; \
    }
// QK for this wave's 16-k slab -> lP2[B], columns w*16..w*16+15 (unchanged)
#define QK_STRIPE(KA, B)                                                      \
    {                                                                         \
        _Pragma("unroll")                                                     \
        for (int jq = 0; jq < 8; jq++) {                                      \
            f32x4 s_ = z;                                                     \
            s_ = __builtin_amdgcn_mfma_f32_16x16x32_bf16(KA[0], Qf[jq][0], s_, 0, 0, 0); \
            s_ = __builtin_amdgcn_mfma_f32_16x16x32_bf16(KA[1], Qf[jq][1], s_, 0, 0, 0); \
            u32 e0 = __float_as_uint(fexp2(s_[0]));                           \
            u32 e1 = __float_as_uint(fexp2(s_[1]));                           \
            u32 e2 = __float_as_uint(fexp2(s_[2]));                           \
            u32 e3 = __float_as_uint(fexp2(s_[3]));                           \
            uint2 pk;                                                         \
            pk.x = __builtin_amdgcn_perm(e1, e0, 0x07060302u);                \
            pk.y = __builtin_amdgcn_perm(e3, e2, 0x07060302u);                \
            *(uint2*)&lP2[B][jq * 16 + l16][w * 16 + quad * 4] = pk;          \
        }                                                                     \
    }
// PV: 32 d x this wave's 32-k half; ONE b128 P-read per jq (was two)
#define PV_STRIPE(VB, B)                                                      \
    {                                                                         \
        _Pragma("unroll")                                                     \
        for (int jq = 0; jq < 8; jq++) {                                      \
            bf16x8 pa = *(const bf16x8*)&lP2[B][jq * 16 + l16][khalf * 32 + quad * 8]; \
            _Pragma("unroll")                                                 \
            for (int jd = 0; jd < 2; jd++)                                    \
                acc[jq][jd] = __builtin_amdgcn_mfma_f32_16x16x32_bf16(pa, VB[jd], acc[jq][jd], 0, 0, 0); \
        }                                                                     \
    }

    bf16x8 kA0[2], kA1[2], vb0[2], vb1[2];
    LOAD_K(kA0, 0)
    LOAD_V(vb0, 0)
    LOAD_K(kA1, 1)
    LOAD_V(vb1, 1)

    QK_STRIPE(kA0, 0)
    __syncthreads();
    for (int it = 0; it < 15; it++) {
        int i = it * 2;
        // stripe i (buf0) PV; QK(i+1)->buf1 first
        QK_STRIPE(kA1, 1)
        LOAD_K(kA0, i + 2)
        PV_STRIPE(vb0, 0)
        LOAD_V(vb0, i + 2)
        __syncthreads();
        // stripe i+1 (buf1) PV; QK(i+2)->buf0
        QK_STRIPE(kA0, 0)
        LOAD_K(kA1, i + 3)
        PV_STRIPE(vb1, 1)
        LOAD_V(vb1, i + 3)
        __syncthreads();
    }
    // stripe 31 QK -> buf1; stripe 30 PV <- buf0
    QK_STRIPE(kA1, 1)
    PV_STRIPE(vb0, 0)
    __syncthreads();
    // stripe 31 PV <- buf1
    PV_STRIPE(vb1, 1)

#undef LOAD_K
#undef LOAD_V
#undef QK_STRIPE
#undef PV_STRIPE

    // ---- epilogue: 2-way k-sum into red (overlays both P buffers) ----
    __syncthreads();
    if (khalf == 0) {
        #pragma unroll
        for (int jq = 0; jq < 8; jq++)
            #pragma unroll
            for (int jd = 0; jd < 2; jd++)
                #pragma unroll
                for (int r = 0; r < 4; r++)
                    red[jq * 16 + quad * 4 + r][dhalf * 32 + jd * 16 + l16] = acc[jq][jd][r];
    }
    __syncthreads();
    if (khalf == 1) {
        #pragma unroll
        for (int jq = 0; jq < 8; jq++)
            #pragma unroll
            for (int jd = 0; jd < 2; jd++)
                #pragma unroll
                for (int r = 0; r < 4; r++)
                    red[jq * 16 + quad * 4 + r][dhalf * 32 + jd * 16 + l16] += acc[jq][jd][r];
    }
    __syncthreads();
    float* dst = acat2 + (long)kcid * 8192 * 256;
    #pragma unroll
    for (int p = 0; p < 8; p++) {
        int row = p * 16 + (t >> 4);
        int ch = (t & 15) * 4;
        float4 o = *(float4*)&red[row][ch];
        *(float4*)&dst[((long)n * SEQ + q0 + row) * 256 + h * 64 + ch] = o;
    }
}

// ---------------------------------------------------------------------------
// Fused tail: LN2 + MLP + residual + transposed store (R12-proven).
// Sums 2 acat2 partials.
// ---------------------------------------------------------------------------
__global__ __launch_bounds__(256) void k_tail(const float* __restrict__ x,
                                              const float* __restrict__ acat2,
                                              const float* __restrict__ lnw,
                                              const float* __restrict__ lnb,
                                              const u16* __restrict__ W1t,
                                              const float* __restrict__ b1v,
                                              const u16* __restrict__ W2t,
                                              const float* __restrict__ b2v,
                                              float* __restrict__ out)
{
    __shared__ __align__(16) unsigned char smem[16448];  // tile fp32 / lT u16
    float (*tile)[257] = (float(*)[257])smem;            // [16][257]
    u16 (*lT)[264] = (u16(*)[264])smem;                  // [16][264] overlay
    __shared__ float aF[16][257];                        // folded acat cache
    __shared__ float mu[16], rs[16];
    __shared__ __align__(16) u16 lH[16][264];

    const long STRIDE = (long)8192 * 256;
    int m0 = blockIdx.x * 16;
    int n = m0 >> 12, s0 = m0 & 4095;
    int t = threadIdx.x, w = t >> 6, lane = t & 63, quad = lane >> 4, l16 = lane & 15;

    {
        int sl = t & 15, cg = t >> 4;
        for (int cc = 0; cc < 256; cc += 16) {
            int c = cc + cg;
            tile[sl][c] = x[(n * 256 + c) * SEQ + s0 + sl];
        }
    }
    __syncthreads();
    for (int s = 0; s < 16; s++) {
        long idx = (long)(m0 + s) * 256 + t;
        float a = acat2[idx] + acat2[idx + STRIDE];
        aF[s][t] = a;
        tile[s][t] += a;
    }
    __syncthreads();
    {
        int l = t & 63;
        for (int rr = 0; rr < 4; rr++) {
            int s = w * 4 + rr;
            float a0 = tile[s][l], a1 = tile[s][l + 64], a2 = tile[s][l + 128], a3 = tile[s][l + 192];
            float sm = a0 + a1 + a2 + a3;
            float sq = a0 * a0 + a1 * a1 + a2 * a2 + a3 * a3;
            for (int off = 32; off; off >>= 1) { sm += __shfl_xor(sm, off); sq += __shfl_xor(sq, off); }
            if (l == 0) {
                float m = sm * (1.f / 256.f);
                mu[s] = m;
                rs[s] = rsqrtf(sq * (1.f / 256.f) - m * m + 1e-5f);
            }
        }
    }
    __syncthreads();
    {
        float ww = lnw[t], bb = lnb[t];
        for (int s = 0; s < 16; s++)
            lH[s][t] = f2bf((tile[s][t] - mu[s]) * rs[s] * ww + bb);
    }
    __syncthreads();

    f32x4 z = {0.f, 0.f, 0.f, 0.f};
    f32x4 acc1[4];
    #pragma unroll
    for (int js = 0; js < 4; js++) acc1[js] = z;
    #pragma unroll
    for (int kc = 0; kc < 8; kc++) {
        bf16x8 b = *(const bf16x8*)&lH[l16][kc * 32 + quad * 8];
        #pragma unroll
        for (int js = 0; js < 4; js++) {
            bf16x8 a = *(const bf16x8*)&W1t[(long)(w * 64 + js * 16 + l16) * 256 + kc * 32 + quad * 8];
            acc1[js] = __builtin_amdgcn_mfma_f32_16x16x32_bf16(a, b, acc1[js], 0, 0, 0);
        }
    }
    #pragma unroll
    for (int js = 0; js < 4; js++) {
        u32 e[4];
        #pragma unroll
        for (int r = 0; r < 4; r++) {
            int j = w * 64 + js * 16 + quad * 4 + r;
            float v = acc1[js][r] + b1v[j];
            float g = 0.5f * v * (1.f + erff(v * 0.70710678118f));
            u32 u = __float_as_uint(g);
            e[r] = u + 0x7fffu + ((u >> 16) & 1u);
        }
        uint2 pk;
        pk.x = __builtin_amdgcn_perm(e[1], e[0], 0x07060302u);
        pk.y = __builtin_amdgcn_perm(e[3], e[2], 0x07060302u);
        *(uint2*)&lT[l16][w * 64 + js * 16 + quad * 4] = pk;
    }
    __syncthreads();
    f32x4 acc2[4];
    #pragma unroll
    for (int cs = 0; cs < 4; cs++) acc2[cs] = z;
    #pragma unroll
    for (int kc = 0; kc < 8; kc++) {
        bf16x8 pa = *(const bf16x8*)&lT[l16][kc * 32 + quad * 8];
        #pragma unroll
        for (int cs = 0; cs < 4; cs++) {
            bf16x8 wb = *(const bf16x8*)&W2t[(long)(w * 64 + cs * 16 + l16) * 256 + kc * 32 + quad * 8];
            acc2[cs] = __builtin_amdgcn_mfma_f32_16x16x32_bf16(pa, wb, acc2[cs], 0, 0, 0);
        }
    }
    #pragma unroll
    for (int cs = 0; cs < 4; cs++) {
        int c = w * 64 + cs * 16 + l16;
        float bj = b2v[c];
        float vv[4];
        #pragma unroll
        for (int r = 0; r < 4; r++)
            vv[r] = acc2[cs][r] + bj + aF[quad * 4 + r][c];
        float4 o = make_float4(vv[0], vv[1], vv[2], vv[3]);
        *(float4*)&out[((long)n * 256 + c) * SEQ + s0 + quad * 4] = o;
    }
}

// ---------------------------------------------------------------------------
extern "C" void kernel_launch(void* const* d_in, const int* in_sizes, int n_in,
                              void* d_out, int out_size, void* d_ws, size_t ws_size,
                              hipStream_t stream) {
    const float* x    = (const float*)d_in[0];
    const float* ln1w = (const float*)d_in[1];
    const float* ln1b = (const float*)d_in[2];
    const float* WQ   = (const float*)d_in[3];
    const float* WK   = (const float*)d_in[4];
    const float* WV   = (const float*)d_in[5];
    const float* ln2w = (const float*)d_in[6];
    const float* ln2b = (const float*)d_in[7];
    const float* W1   = (const float*)d_in[8];
    const float* b1   = (const float*)d_in[9];
    const float* W2   = (const float*)d_in[10];
    const float* b2   = (const float*)d_in[11];
    float* out = (float*)d_out;

    char* p = (char*)d_ws;
    u16* norm   = (u16*)p;   p += (size_t)8192 * 256 * 2;
    u16* BtQKV  = (u16*)p;   p += (size_t)768 * 256 * 2;
    u16* W1t    = (u16*)p;   p += (size_t)256 * 256 * 2;
    u16* W2t    = (u16*)p;   p += (size_t)256 * 256 * 2;
    u16* Qb     = (u16*)p;   p += (size_t)NHT * SEQ * 64 * 2;
    u16* Kb     = (u16*)p;   p += (size_t)NHT * SEQ * 64 * 2;
    u16* VtT    = (u16*)p;   p += (size_t)NHT * SEQ * 64 * 2;
    float* D2   = (float*)p; p += (size_t)4 * NHT * SEQ * 4;
    float* acat2= (float*)p; p += (size_t)2 * 8192 * 256 * 4;
    // Vf (f32 transposed V, 8.4 MB) overlays acat2: qkv writes it, vdiv
    // consumes it, THEN pass2 overwrites acat2 — stream-ordered, no extra ws.
    float* Vf   = acat2;

    k_prep<<<1536, 256, 0, stream>>>(x, ln1w, ln1b, WQ, WK, WV, W1, W2,
                                     norm, BtQKV, W1t, W2t);
    k_qkv<<<dim3(128, 6), 256, 0, stream>>>(norm, BtQKV, Qb, Kb, Vf);
    k_pass1<<<1024, 256, 0, stream>>>(Qb, Kb, D2);
    k_vdiv<<<512, 256, 0, stream>>>(Vf, D2, VtT);
    k_pass2<<<512, 256, 0, stream>>>(Qb, Kb, VtT, acat2);
    k_tail<<<512, 256, 0, stream>>>(x, acat2, ln2w, ln2b, W1t, b1, W2t, b2, out);
}